// Round 14
// baseline (89.048 us; speedup 1.0000x reference)
//
#include <hip/hip_runtime.h>

// CCQC classifier, GEMM formulation. R14: DS-pipe offload in build.
//   0. make_prog: 101-gate pre-adjointed packed program (execution order)
//      -> GLOBAL ws. Build reads it via uniform loads (scalar/VMEM pipe),
//      removing ~404 wave-uniform ds_read ops per wave (R13 analysis: the
//      DS pipe, not VALU, is qprep's floor -- pk-asm was neutral).
//   1. qprep (blocks 0..1023): build rows of U via REVERSED ADJOINT circuit.
//      256-thread block per basis state; j = (wv<<8)|(k<<6)|lane, 4 f32x2
//      regs/lane. Lane-xor shuffles for masks 1,2 via DPP quad_perm (VALU
//      pipe) instead of ds_swizzle. Cross-wave gates (j-bits 8,9) via
//      double-buffered LDS exchange, 1 barrier each.
//      Wt interleaved: row 2j=Re, 2j+1=Im.
//      Blocks >=1024: xconv X fp32 -> fp16, packed cvt_pkrtz, 832 cols only.
//   2. gemm_z: C = Xh * Wt^T, M=8192 N=2048 K=832, 128x128 tile, BK=64,
//      512 threads = 8 waves (4M x 2N), double-buffered global_load_lds,
//      XOR bank-swizzle (both-sides), fused |psi|^2 epilogue -> 32 partials.
//   3. nll_part (32 blocks) + nll_final: log-softmax NLL, mean.

namespace {

typedef float f32x2 __attribute__((ext_vector_type(2)));
typedef __fp16 fp16x2 __attribute__((ext_vector_type(2)));   // cvt_pkrtz's type
typedef _Float16 f16x8 __attribute__((ext_vector_type(8)));
typedef float f32x4v __attribute__((ext_vector_type(4)));

// ---- packed dual-f32 ops (VOP3P), untied operands ----
__device__ __forceinline__ f32x2 pk_mul(f32x2 a, f32x2 b) {
  f32x2 d;
  asm("v_pk_mul_f32 %0, %1, %2" : "=v"(d) : "v"(a), "v"(b));
  return d;
}
__device__ __forceinline__ f32x2 pk_fma(f32x2 a, f32x2 b, f32x2 c) {
  f32x2 d;
  asm("v_pk_fma_f32 %0, %1, %2, %3" : "=v"(d) : "v"(a), "v"(b), "v"(c));
  return d;
}
// b's halves swapped via op_sel (no explicit swap move).
__device__ __forceinline__ f32x2 pk_fma_swap1(f32x2 a, f32x2 b, f32x2 c) {
  f32x2 d;
  asm("v_pk_fma_f32 %0, %1, %2, %3 op_sel:[0,1,0] op_sel_hi:[1,0,1]"
      : "=v"(d) : "v"(a), "v"(b), "v"(c));
  return d;
}
// complex product: coeff pre-packed cr2={re,re}, ci2={-im,im}.
__device__ __forceinline__ f32x2 cmulp(f32x2 cr2, f32x2 ci2, f32x2 v) {
  return pk_fma_swap1(ci2, v, pk_mul(cr2, v));
}
// acc + coeff (*) v
__device__ __forceinline__ f32x2 cmad(f32x2 acc, f32x2 cr2, f32x2 ci2, f32x2 v) {
  return pk_fma_swap1(ci2, v, pk_fma(cr2, v, acc));
}

__device__ __forceinline__ f32x2 shfl_xor2(f32x2 v, int lm) {
  f32x2 r;
  r.x = __shfl_xor(v.x, lm, 64);
  r.y = __shfl_xor(v.y, lm, 64);
  return r;
}
// DPP quad_perm lane-xor (VALU pipe, not DS). 0xB1 = xor1, 0x4E = xor2.
template <int CTRL>
__device__ __forceinline__ f32x2 dpp_xor2(f32x2 v) {
  f32x2 r;
  const int ix = __builtin_bit_cast(int, v.x);
  const int iy = __builtin_bit_cast(int, v.y);
  r.x = __builtin_bit_cast(float,
      __builtin_amdgcn_update_dpp(0, ix, CTRL, 0xF, 0xF, true));
  r.y = __builtin_bit_cast(float,
      __builtin_amdgcn_update_dpp(0, iy, CTRL, 0xF, 0xF, true));
  return r;
}
// lm is compile-time after full unrolling: masks 1,2 fold to DPP.
__device__ __forceinline__ f32x2 shfl_fast(f32x2 v, const int lm) {
  if (lm == 1) return dpp_xor2<0xB1>(v);
  if (lm == 2) return dpp_xor2<0x4E>(v);
  return shfl_xor2(v, lm);
}
__device__ __forceinline__ f32x2 sel2(bool c, f32x2 a, f32x2 b) {
  f32x2 r; r.x = c ? a.x : b.x; r.y = c ? a.y : b.y; return r;
}

struct c2 { float r, i; };
struct m2c { c2 a00, a01, a10, a11; };

__device__ __forceinline__ c2 cmul(c2 x, c2 y) { return {x.r*y.r - x.i*y.i, x.r*y.i + x.i*y.r}; }
__device__ __forceinline__ c2 cadd(c2 x, c2 y) { return {x.r + y.r, x.i + y.i}; }
__device__ __forceinline__ c2 conjc(c2 a) { return {a.r, -a.i}; }
__device__ __forceinline__ m2c mmul(m2c A, m2c B) {
  m2c C;
  C.a00 = cadd(cmul(A.a00, B.a00), cmul(A.a01, B.a10));
  C.a01 = cadd(cmul(A.a00, B.a01), cmul(A.a01, B.a11));
  C.a10 = cadd(cmul(A.a10, B.a00), cmul(A.a11, B.a10));
  C.a11 = cadd(cmul(A.a10, B.a01), cmul(A.a11, B.a11));
  return C;
}
__device__ __forceinline__ m2c mrx(float t) {
  float c = cosf(0.5f * t), s = sinf(0.5f * t);
  return { {c, 0.f}, {0.f, -s}, {0.f, -s}, {c, 0.f} };
}
__device__ __forceinline__ m2c mrz(float t) {
  float c = cosf(0.5f * t), s = sinf(0.5f * t);
  return { {c, -s}, {0.f, 0.f}, {0.f, 0.f}, {c, s} };
}

// Pre-adjointed packed program -> global ws. Slot layout (exec order of the
// reversed-adjoint circuit):
//   dd=0 (d=4): slot0 = U0; 1..10 = CU i=9..0; 11..20 = U1 i=9..0.
//   dd>=1: base=21+(dd-1)*20: 0..9 = CU i=9..0; 10..19 = U1 i=9..0.
// U0[d<4] pre-fused into U1[d+1, i=0]. 101 slots x 16 floats:
// per adjoint entry A of {00,01,10,11}: {A.re, A.re, -A.im, A.im}.
__global__ void make_prog(const float* __restrict__ w, const float* __restrict__ w1,
                          const float* __restrict__ w2, float* __restrict__ prog) {
  const int t = threadIdx.x;
  m2c U{}; int slot = -1;
  if (t < 50) {
    const int d = t / 10, i = t % 10;
    const float* p = w + (d * 10 + i) * 5;
    U = mmul(mrx(p[2]), mmul(mrz(p[1]), mrx(p[0])));
    if (i == 0 && d > 0) {
      m2c U0 = mmul(mrz(w2[d - 1]), mrx(w1[d - 1]));
      U = mmul(U, U0);
    }
    const int dd = 4 - d;
    const int base = (dd == 0) ? 0 : 21 + (dd - 1) * 20;
    slot = base + ((d == 4) ? 11 : 10) + (9 - i);
  } else if (t < 100) {
    const int s = t - 50; const int d = s / 10, i = s % 10;
    const float* p = w + (d * 10 + i) * 5;
    U = mmul(mrx(p[4]), mrz(p[3]));
    const int dd = 4 - d;
    const int base = (dd == 0) ? 0 : 21 + (dd - 1) * 20;
    slot = base + ((d == 4) ? 1 : 0) + (9 - i);
  } else if (t == 100) {
    U = mmul(mrz(w2[4]), mrx(w1[4]));
    slot = 0;
  }
  if (slot >= 0) {
    const c2 A[4] = {conjc(U.a00), conjc(U.a10), conjc(U.a01), conjc(U.a11)};
    float* o = prog + slot * 16;
    #pragma unroll
    for (int q = 0; q < 4; ++q) {
      o[q*4 + 0] = A[q].r; o[q*4 + 1] = A[q].r;
      o[q*4 + 2] = -A[q].i; o[q*4 + 3] = A[q].i;
    }
  }
}

struct MatP { f32x2 u00r, u00i, u01r, u01i, u10r, u10i, u11r, u11i; };

// Uniform global load (scalar/VMEM pipe -- intentionally NOT LDS).
__device__ __forceinline__ MatP ldmatG(const float* __restrict__ prog, int slot) {
  const float4* p = reinterpret_cast<const float4*>(prog + slot * 16);
  float4 a = p[0], b = p[1], c = p[2], d = p[3];
  MatP m;
  m.u00r = f32x2{a.x, a.y}; m.u00i = f32x2{a.z, a.w};
  m.u01r = f32x2{b.x, b.y}; m.u01i = f32x2{b.z, b.w};
  m.u10r = f32x2{c.x, c.y}; m.u10i = f32x2{c.z, c.w};
  m.u11r = f32x2{d.x, d.y}; m.u11i = f32x2{d.z, d.w};
  return m;
}

// ---- 4-reg (4 waves/state) gate appliers ----
__device__ __forceinline__ void g_xlane(f32x2 (&s)[4], const int lm,
                                        const f32x2 cAr, const f32x2 cAi,
                                        const f32x2 cBr, const f32x2 cBi,
                                        const int cm_reg) {
  #pragma unroll
  for (int k = 0; k < 4; ++k) {
    if (cm_reg && !(k & cm_reg)) continue;
    const f32x2 p = shfl_fast(s[k], lm);
    s[k] = cmad(cmulp(cAr, cAi, s[k]), cBr, cBi, p);
  }
}
__device__ __forceinline__ void g_local(f32x2 (&s)[4], const int kb, const MatP m,
                                        const int cm_reg) {
  const int tm = 1 << kb;
  #pragma unroll
  for (int k0 = 0; k0 < 4; ++k0) {
    if (k0 & tm) continue;
    if (cm_reg && !(k0 & cm_reg)) continue;
    const int k1 = k0 | tm;
    const f32x2 a = s[k0], b = s[k1];
    s[k0] = cmad(cmulp(m.u00r, m.u00i, a), m.u01r, m.u01i, b);
    s[k1] = cmad(cmulp(m.u10r, m.u10i, a), m.u11r, m.u11i, b);
  }
}
// Single barrier per exchange: caller alternates lxb between two buffers.
__device__ __forceinline__ void g_xwave(f32x2 (&s)[4], f32x2* lxb, const int wv,
                                        const int lane, const int tb,
                                        const f32x2 cAr, const f32x2 cAi,
                                        const f32x2 cBr, const f32x2 cBi,
                                        const int cm_reg) {
  #pragma unroll
  for (int k = 0; k < 4; ++k) lxb[(wv * 4 + k) * 64 + lane] = s[k];
  __syncthreads();
  const int pw = wv ^ (1 << tb);
  #pragma unroll
  for (int k = 0; k < 4; ++k) {
    if (cm_reg && !(k & cm_reg)) continue;
    const f32x2 p = lxb[(pw * 4 + k) * 64 + lane];
    s[k] = cmad(cmulp(cAr, cAi, s[k]), cBr, cBi, p);
  }
}

__device__ __forceinline__ void apply_gate(f32x2 (&s)[4], f32x2* lxb, const int wv,
                                           const int lane, const MatP mIn,
                                           const int bt, const int bc) {
  MatP m = mIn;
  const f32x2 oner{1.f, 1.f}, zero{0.f, 0.f};
  int cm_reg = 0;
  bool fold = false, cl = true;
  if (bc >= 8)      { cl = ((wv >> (bc - 8)) & 1) != 0; fold = true; }
  else if (bc >= 6) { cm_reg = 1 << (bc - 6); }
  else if (bc >= 0) { cl = ((lane >> bc) & 1) != 0; fold = true; }

  if (bt >= 8) {
    const int tb = bt - 8;
    const bool hi = ((wv >> tb) & 1) != 0;
    f32x2 cAr = sel2(hi, m.u11r, m.u00r), cAi = sel2(hi, m.u11i, m.u00i);
    f32x2 cBr = sel2(hi, m.u10r, m.u01r), cBi = sel2(hi, m.u10i, m.u01i);
    if (fold) {
      cAr = sel2(cl, cAr, oner); cAi = sel2(cl, cAi, zero);
      cBr = sel2(cl, cBr, zero); cBi = sel2(cl, cBi, zero);
    }
    g_xwave(s, lxb, wv, lane, tb, cAr, cAi, cBr, cBi, cm_reg);
  } else if (bt >= 6) {
    if (fold) {
      m.u00r = sel2(cl, m.u00r, oner); m.u00i = sel2(cl, m.u00i, zero);
      m.u01r = sel2(cl, m.u01r, zero); m.u01i = sel2(cl, m.u01i, zero);
      m.u10r = sel2(cl, m.u10r, zero); m.u10i = sel2(cl, m.u10i, zero);
      m.u11r = sel2(cl, m.u11r, oner); m.u11i = sel2(cl, m.u11i, zero);
    }
    g_local(s, bt - 6, m, cm_reg);
  } else {
    const bool hi = ((lane >> bt) & 1) != 0;
    f32x2 cAr = sel2(hi, m.u11r, m.u00r), cAi = sel2(hi, m.u11i, m.u00i);
    f32x2 cBr = sel2(hi, m.u10r, m.u01r), cBi = sel2(hi, m.u10i, m.u01i);
    if (fold) {
      cAr = sel2(cl, cAr, oner); cAi = sel2(cl, cAi, zero);
      cBr = sel2(cl, cBr, zero); cBi = sel2(cl, cBi, zero);
    }
    g_xlane(s, 1 << bt, cAr, cAi, cBr, cBi, cm_reg);
  }
}

// Fused prep. Blocks <1024: build row n=blockIdx of U (4 waves, 4 regs/lane).
// Blocks >=1024: xconv (832 cols, packed cvt).
__global__ __launch_bounds__(256) void qprep(const float* __restrict__ prog,
                                             const float* __restrict__ x,
                                             _Float16* __restrict__ Wt,
                                             _Float16* __restrict__ Xh) {
  const int tid = threadIdx.x;
  if (blockIdx.x >= 1024) {
    // ---- xconv: fp32 -> fp16, cols [0,832) only (gemm reads K=832) ----
    const int t = (blockIdx.x - 1024) * 256 + tid;
    const int b = t >> 7;
    const int j = (t & 127) * 8;
    if (j >= 832) return;
    union { fp16x2 h2[4]; f16x8 h8; } u;
    if (j < 784) {
      const float4* p = reinterpret_cast<const float4*>(x + (size_t)b * 784 + j);
      const float4 v0 = p[0], v1 = p[1];
      u.h2[0] = __builtin_amdgcn_cvt_pkrtz(v0.x, v0.y);
      u.h2[1] = __builtin_amdgcn_cvt_pkrtz(v0.z, v0.w);
      u.h2[2] = __builtin_amdgcn_cvt_pkrtz(v1.x, v1.y);
      u.h2[3] = __builtin_amdgcn_cvt_pkrtz(v1.z, v1.w);
    } else {
      #pragma unroll
      for (int q = 0; q < 4; ++q) u.h2[q] = __builtin_amdgcn_cvt_pkrtz(0.f, 0.f);
    }
    *reinterpret_cast<f16x8*>(Xh + (size_t)b * 1024 + j) = u.h8;
    return;
  }

  // ---- build_W ----
  __shared__ f32x2 lx[2][1024];   // double-buffered exchange (16 KB)

  const int lane = tid & 63;
  const int wv = tid >> 6;
  const int n = blockIdx.x;

  f32x2 s[4];
  #pragma unroll
  for (int k = 0; k < 4; ++k) {
    const int j = (wv << 8) | (k << 6) | lane;
    s[k].x = (j == n) ? 1.f : 0.f;
    s[k].y = 0.f;
  }

  int p = 0, ph = 0;
  #pragma unroll
  for (int dd = 0; dd < 5; ++dd) {
    const int d = 4 - dd;
    if (d == 4) {
      apply_gate(s, &lx[ph & 1][0], wv, lane, ldmatG(prog, p), 9, -1);
      ++p; ++ph;
    }
    const int r = (d & 1) ? 3 : 1;
    #pragma unroll
    for (int ii = 0; ii < 10; ++ii) {
      const int i = 9 - ii;
      const int c = (i + r) % 10;
      const int bt = 9 - i, bc = 9 - c;
      apply_gate(s, &lx[ph & 1][0], wv, lane, ldmatG(prog, p), bt, bc);
      ++p; if (bt >= 8) ++ph;
    }
    #pragma unroll
    for (int ii = 0; ii < 10; ++ii) {
      const int i = 9 - ii;
      const int bt = 9 - i;
      apply_gate(s, &lx[ph & 1][0], wv, lane, ldmatG(prog, p), bt, -1);
      ++p; if (bt >= 8) ++ph;
    }
  }

  // psi = U^dagger e_n => U[n][j] = (s.x, -s.y)
  #pragma unroll
  for (int k = 0; k < 4; ++k) {
    const int j = (wv << 8) | (k << 6) | lane;
    Wt[(size_t)(2 * n) * 1024 + j] = (_Float16)s[k].x;
    Wt[(size_t)(2 * n + 1) * 1024 + j] = (_Float16)(-s[k].y);
  }
}

// ---------------- LDS-staged GEMM ----------------
// Tile 128(M) x 128(N-rows, interleaved re/im = 64 js), BK=64, 13 K-steps.
// 512 threads = 8 waves (4M x 2N), wave tile 32x64 -> 16 waves/CU.
// LDS swizzle: row r's 8 16B-slots permuted s -> s^(r&7); staged with linear
// LDS dest + swizzled GLOBAL source; read with same XOR (rule #21).
#define GZ_NSTEP 13

__device__ __forceinline__ void stage_tiles(const _Float16* __restrict__ gA,
                                            const _Float16* __restrict__ gB,
                                            _Float16* sA, _Float16* sB,
                                            int k0, int wv, int lane) {
  const int rIn = lane >> 3;                    // row within chunk (0..7)
  const int colh = ((lane & 7) ^ rIn) * 8;      // swizzled source 16B-slot
  #pragma unroll
  for (int c = 0; c < 2; ++c) {
    const int chunk = wv * 2 + c;
    const size_t grow = (size_t)(chunk * 8 + rIn) * 1024 + k0 + colh;
    auto* la = (__attribute__((address_space(3))) void*)(sA + chunk * 512 + lane * 8);
    __builtin_amdgcn_global_load_lds(
        (const __attribute__((address_space(1))) void*)(gA + grow), la, 16, 0, 0);
    auto* lb = (__attribute__((address_space(3))) void*)(sB + chunk * 512 + lane * 8);
    __builtin_amdgcn_global_load_lds(
        (const __attribute__((address_space(1))) void*)(gB + grow), lb, 16, 0, 0);
  }
}

__device__ __forceinline__ int lds_off(int row, int slot) {
  return row * 64 + ((slot ^ (row & 7)) * 8);
}

__global__ __launch_bounds__(512) void gemm_z(const _Float16* __restrict__ Xh,
                                              const _Float16* __restrict__ Wt,
                                              float* __restrict__ part, int B) {
  __shared__ _Float16 smA[2][128 * 64];
  __shared__ _Float16 smB[2][128 * 64];

  const int tid = threadIdx.x;
  const int lane = tid & 63;
  const int wv = tid >> 6;        // 0..7
  const int wm = wv >> 1;         // 0..3 (M)
  const int wn = wv & 1;          // 0..1 (N)
  const int row0 = blockIdx.x * 128;
  const int n0 = blockIdx.y * 128;

  const _Float16* gA = Xh + (size_t)row0 * 1024;
  const _Float16* gB = Wt + (size_t)n0 * 1024;

  const int lr = lane & 15;
  const int lq = lane >> 4;       // 0..3: which 8-f16 K-slot within 32

  f32x4v acc[2][4];
  #pragma unroll
  for (int m = 0; m < 2; ++m)
    #pragma unroll
    for (int f = 0; f < 4; ++f) acc[m][f] = f32x4v{0.f, 0.f, 0.f, 0.f};

  stage_tiles(gA, gB, smA[0], smB[0], 0, wv, lane);
  __syncthreads();

  for (int t = 0; t < GZ_NSTEP; ++t) {
    const int cur = t & 1;
    if (t + 1 < GZ_NSTEP)
      stage_tiles(gA, gB, smA[cur ^ 1], smB[cur ^ 1], (t + 1) * 64, wv, lane);

    #pragma unroll
    for (int kk = 0; kk < 2; ++kk) {
      const int slot = kk * 4 + lq;
      f16x8 a[2], b[4];
      #pragma unroll
      for (int m = 0; m < 2; ++m) {
        const int row = wm * 32 + m * 16 + lr;
        a[m] = *reinterpret_cast<const f16x8*>(&smA[cur][lds_off(row, slot)]);
      }
      #pragma unroll
      for (int f = 0; f < 4; ++f) {
        const int row = wn * 64 + f * 16 + lr;
        b[f] = *reinterpret_cast<const f16x8*>(&smB[cur][lds_off(row, slot)]);
      }
      #pragma unroll
      for (int m = 0; m < 2; ++m)
        #pragma unroll
        for (int f = 0; f < 4; ++f)
          acc[m][f] = __builtin_amdgcn_mfma_f32_16x16x32_f16(a[m], b[f], acc[m][f], 0, 0, 0);
    }
    __syncthreads();
  }

  // Epilogue: sum of squares over the wave's 64 N-rows (= 32 js re/im pairs).
  const int pp = blockIdx.y * 2 + wn;
  #pragma unroll
  for (int m = 0; m < 2; ++m) {
    f32x4v p = f32x4v{0.f, 0.f, 0.f, 0.f};
    #pragma unroll
    for (int f = 0; f < 4; ++f) p += acc[m][f] * acc[m][f];
    #pragma unroll
    for (int msk = 1; msk < 16; msk <<= 1) {
      p.x += __shfl_xor(p.x, msk, 64);
      p.y += __shfl_xor(p.y, msk, 64);
      p.z += __shfl_xor(p.z, msk, 64);
      p.w += __shfl_xor(p.w, msk, 64);
    }
    if (lr == 0) {
      const int rbase = row0 + wm * 32 + m * 16 + lq * 4;
      float* dst = part + (size_t)pp * B + rbase;
      dst[0] = p.x; dst[1] = p.y; dst[2] = p.z; dst[3] = p.w;
    }
  }
}

// ---- NLL: 32-block partial + final reduce (deterministic) ----
__global__ __launch_bounds__(256) void nll_part(const float* __restrict__ part,
                                                const int* __restrict__ y,
                                                float* __restrict__ out2, int B) {
  const int row = blockIdx.x * 256 + threadIdx.x;
  float q0 = 0.f, q1 = 0.f, nn = 0.f;
  #pragma unroll
  for (int pp = 0; pp < 32; ++pp) {
    const float P = part[(size_t)pp * B + row];
    q0 += (pp & 16) ? -P : P;
    q1 += (pp & 8) ? -P : P;
    nn += P;
  }
  const float z0 = q0 / nn, z1 = q1 / nn;
  const float mx = fmaxf(z0, z1);
  const float lse = mx + logf(expf(z0 - mx) + expf(z1 - mx));
  const float ly = (y[row] == 0) ? z0 : z1;
  float s = lse - ly;
  #pragma unroll
  for (int msk = 1; msk < 64; msk <<= 1) s += __shfl_xor(s, msk, 64);
  __shared__ float red[4];
  if ((threadIdx.x & 63) == 0) red[threadIdx.x >> 6] = s;
  __syncthreads();
  if (threadIdx.x == 0) out2[blockIdx.x] = red[0] + red[1] + red[2] + red[3];
}

__global__ void nll_final(const float* __restrict__ out2, float* __restrict__ out,
                          int nblk, float scale) {
  const int t = threadIdx.x;
  float s = (t < nblk) ? out2[t] : 0.f;
  #pragma unroll
  for (int msk = 1; msk < 64; msk <<= 1) s += __shfl_xor(s, msk, 64);
  if (t == 0) out[0] = s * scale;
}

} // namespace

extern "C" void kernel_launch(void* const* d_in, const int* in_sizes, int n_in,
                              void* d_out, int out_size, void* d_ws, size_t ws_size,
                              hipStream_t stream) {
  const float* x  = (const float*)d_in[0];
  const int*   y  = (const int*)d_in[1];
  const float* w  = (const float*)d_in[2];
  const float* w1 = (const float*)d_in[3];
  const float* w2 = (const float*)d_in[4];
  float* out = (float*)d_out;

  const int B = in_sizes[0] / 784;      // 8192

  char* ws = (char*)d_ws;
  _Float16* Wt   = (_Float16*)ws;                                // 4 MB
  _Float16* Xh   = (_Float16*)(ws + (size_t)2048 * 1024 * 2);    // 16 MB
  float*    part = (float*)(ws + (size_t)2048 * 1024 * 2 + (size_t)B * 1024 * 2);
  float*    out2 = part + (size_t)32 * B;
  float*    prog = out2 + 64;           // 101*16 floats

  make_prog<<<1, 128, 0, stream>>>(w, w1, w2, prog);
  qprep<<<1024 + (B * 128) / 256, 256, 0, stream>>>(prog, x, Wt, Xh);
  gemm_z<<<dim3(B / 128, 16), 512, 0, stream>>>(Xh, Wt, part, B);
  nll_part<<<B / 256, 256, 0, stream>>>(part, y, out2, B);
  nll_final<<<1, 64, 0, stream>>>(out2, out, B / 256, 1.0f / (float)B);
}

// Round 15
// 87.412 us; speedup vs baseline: 1.0187x; 1.0187x over previous
//
#include <hip/hip_runtime.h>

// CCQC classifier, GEMM formulation. R15: GATE FUSION 101 -> 69 ops.
//   Commutation-verified fusion: CU[i](d) absorbs U1[i](d+1) when
//   (i - r(d)) mod 10 <= i  (r=1 layers: i>=1; r=3 layers: i>=3) = 32 pairs.
//   Fused op = ctrl-select gate {ctrl=1: adj(CU)*adj(U1); ctrl=0: adj(U1)} --
//   same per-amp cost as a single gate (per-k/lane compile-time select).
//   0. make_prog: 69-op program (A0|A1 pairs, 32 floats/op) -> global ws.
//   1. qprep (blocks 0..1023): build rows of U, 4 waves x 4 f32x2/lane;
//      gates via VMEM program loads, DPP for xor1/2 shuffles, double-buffered
//      LDS exchange (1 barrier) for j-bits 8,9. Wt rows 2j=Re, 2j+1=Im.
//      Blocks >=1024: xconv fp32 -> fp16, 832 cols.
//   2. gemm_z: 128x128 tile BK=64, 8 waves, global_load_lds + XOR swizzle,
//      fused |psi|^2 epilogue -> 32 chunk partials.
//   3. nll_part + nll_final.

namespace {

typedef float f32x2 __attribute__((ext_vector_type(2)));
typedef __fp16 fp16x2 __attribute__((ext_vector_type(2)));
typedef _Float16 f16x8 __attribute__((ext_vector_type(8)));
typedef float f32x4v __attribute__((ext_vector_type(4)));

// ---- packed dual-f32 ops (VOP3P), untied operands ----
__device__ __forceinline__ f32x2 pk_mul(f32x2 a, f32x2 b) {
  f32x2 d;
  asm("v_pk_mul_f32 %0, %1, %2" : "=v"(d) : "v"(a), "v"(b));
  return d;
}
__device__ __forceinline__ f32x2 pk_fma(f32x2 a, f32x2 b, f32x2 c) {
  f32x2 d;
  asm("v_pk_fma_f32 %0, %1, %2, %3" : "=v"(d) : "v"(a), "v"(b), "v"(c));
  return d;
}
__device__ __forceinline__ f32x2 pk_fma_swap1(f32x2 a, f32x2 b, f32x2 c) {
  f32x2 d;
  asm("v_pk_fma_f32 %0, %1, %2, %3 op_sel:[0,1,0] op_sel_hi:[1,0,1]"
      : "=v"(d) : "v"(a), "v"(b), "v"(c));
  return d;
}
__device__ __forceinline__ f32x2 cmulp(f32x2 cr2, f32x2 ci2, f32x2 v) {
  return pk_fma_swap1(ci2, v, pk_mul(cr2, v));
}
__device__ __forceinline__ f32x2 cmad(f32x2 acc, f32x2 cr2, f32x2 ci2, f32x2 v) {
  return pk_fma_swap1(ci2, v, pk_fma(cr2, v, acc));
}

__device__ __forceinline__ f32x2 shfl_xor2(f32x2 v, int lm) {
  f32x2 r;
  r.x = __shfl_xor(v.x, lm, 64);
  r.y = __shfl_xor(v.y, lm, 64);
  return r;
}
template <int CTRL>
__device__ __forceinline__ f32x2 dpp_xor2(f32x2 v) {
  f32x2 r;
  const int ix = __builtin_bit_cast(int, v.x);
  const int iy = __builtin_bit_cast(int, v.y);
  r.x = __builtin_bit_cast(float,
      __builtin_amdgcn_update_dpp(0, ix, CTRL, 0xF, 0xF, true));
  r.y = __builtin_bit_cast(float,
      __builtin_amdgcn_update_dpp(0, iy, CTRL, 0xF, 0xF, true));
  return r;
}
__device__ __forceinline__ f32x2 shfl_fast(f32x2 v, const int lm) {
  if (lm == 1) return dpp_xor2<0xB1>(v);
  if (lm == 2) return dpp_xor2<0x4E>(v);
  return shfl_xor2(v, lm);
}
__device__ __forceinline__ f32x2 sel2(bool c, f32x2 a, f32x2 b) {
  f32x2 r; r.x = c ? a.x : b.x; r.y = c ? a.y : b.y; return r;
}

struct c2 { float r, i; };
struct m2c { c2 a00, a01, a10, a11; };

__device__ __forceinline__ c2 cmul(c2 x, c2 y) { return {x.r*y.r - x.i*y.i, x.r*y.i + x.i*y.r}; }
__device__ __forceinline__ c2 cadd(c2 x, c2 y) { return {x.r + y.r, x.i + y.i}; }
__device__ __forceinline__ c2 conjc(c2 a) { return {a.r, -a.i}; }
__device__ __forceinline__ m2c mmul(m2c A, m2c B) {
  m2c C;
  C.a00 = cadd(cmul(A.a00, B.a00), cmul(A.a01, B.a10));
  C.a01 = cadd(cmul(A.a00, B.a01), cmul(A.a01, B.a11));
  C.a10 = cadd(cmul(A.a10, B.a00), cmul(A.a11, B.a10));
  C.a11 = cadd(cmul(A.a10, B.a01), cmul(A.a11, B.a11));
  return C;
}
__device__ __forceinline__ m2c madj(m2c U) {
  return { conjc(U.a00), conjc(U.a10), conjc(U.a01), conjc(U.a11) };
}
__device__ __forceinline__ m2c mrx(float t) {
  float c = cosf(0.5f * t), s = sinf(0.5f * t);
  return { {c, 0.f}, {0.f, -s}, {0.f, -s}, {c, 0.f} };
}
__device__ __forceinline__ m2c mrz(float t) {
  float c = cosf(0.5f * t), s = sinf(0.5f * t);
  return { {c, -s}, {0.f, 0.f}, {0.f, 0.f}, {c, s} };
}

// fusable(d,i): CU[i](d) absorbs U1[i](d+1). r(d)=1 (d even): i>=1; r=3: i>=3.
__device__ __forceinline__ bool fusable(int d, int i) {
  return (d & 1) ? (i >= 3) : (i >= 1);
}

// 69-op program, 32 floats/op = [A0 packed 16 | A1 packed 16].
// pack(e) = {e.re, e.re, -e.im, e.im} per entry a00,a01,a10,a11.
// Exec order (reversed-adjoint): per dd (d=4-dd):
//   d==4: U0(4).  Then CU(d) i=9..0 (fused pair if d<=3 && fusable(d,i)).
//   Then U1(d) i=9..0, skipped if d>=1 && fusable(d-1,i) (absorbed).
// U0(d<4) pre-fused into U1(d+1, i=0) (i=0 never pair-fused).
__global__ void make_prog(const float* __restrict__ w, const float* __restrict__ w1,
                          const float* __restrict__ w2, float* __restrict__ prog) {
  const int t = threadIdx.x;
  // walk the enumeration to find op t
  int kind = -1, od = 0, oi = 0, p = 0;
  for (int dd = 0; dd < 5; ++dd) {
    const int d = 4 - dd;
    if (d == 4) { if (p == t) kind = 0; ++p; }
    for (int ii = 0; ii < 10; ++ii) {
      const int i = 9 - ii;
      if (p == t) { kind = (d <= 3 && fusable(d, i)) ? 2 : 1; od = d; oi = i; }
      ++p;
    }
    for (int ii = 0; ii < 10; ++ii) {
      const int i = 9 - ii;
      if (d >= 1 && fusable(d - 1, i)) continue;
      if (p == t) { kind = 3; od = d; oi = i; }
      ++p;
    }
  }
  if (kind < 0) return;

  auto u1mat = [&](int d, int i) -> m2c {
    const float* pw = w + (d * 10 + i) * 5;
    m2c U = mmul(mrx(pw[2]), mmul(mrz(pw[1]), mrx(pw[0])));
    if (i == 0 && d > 0) {
      m2c U0 = mmul(mrz(w2[d - 1]), mrx(w1[d - 1]));
      U = mmul(U, U0);
    }
    return U;
  };
  auto cumat = [&](int d, int i) -> m2c {
    const float* pw = w + (d * 10 + i) * 5;
    return mmul(mrx(pw[4]), mrz(pw[3]));
  };

  m2c A0{}, A1{};
  if (kind == 0) {            // U0(4)
    A0 = madj(mmul(mrz(w2[4]), mrx(w1[4])));
    A1 = A0;
  } else if (kind == 1) {     // CU single
    A0 = madj(cumat(od, oi));
    A1 = A0;
  } else if (kind == 2) {     // CU fused with U1(d+1,i)
    m2c V1 = madj(u1mat(od + 1, oi));
    m2c VC = madj(cumat(od, oi));
    A0 = V1;                  // ctrl=0: adj(U1) only
    A1 = mmul(VC, V1);        // ctrl=1: adj(CU) * adj(U1)
  } else {                    // U1
    A0 = madj(u1mat(od, oi));
    A1 = A0;
  }

  float* o = prog + t * 32;
  const c2 e0[4] = {A0.a00, A0.a01, A0.a10, A0.a11};
  const c2 e1[4] = {A1.a00, A1.a01, A1.a10, A1.a11};
  #pragma unroll
  for (int q = 0; q < 4; ++q) {
    o[q*4 + 0] = e0[q].r; o[q*4 + 1] = e0[q].r;
    o[q*4 + 2] = -e0[q].i; o[q*4 + 3] = e0[q].i;
    o[16 + q*4 + 0] = e1[q].r; o[16 + q*4 + 1] = e1[q].r;
    o[16 + q*4 + 2] = -e1[q].i; o[16 + q*4 + 3] = e1[q].i;
  }
}

struct MatP { f32x2 u00r, u00i, u01r, u01i, u10r, u10i, u11r, u11i; };

__device__ __forceinline__ MatP ldmatG2(const float* __restrict__ prog, int slot, int half) {
  const float4* p = reinterpret_cast<const float4*>(prog + slot * 32 + half * 16);
  float4 a = p[0], b = p[1], c = p[2], d = p[3];
  MatP m;
  m.u00r = f32x2{a.x, a.y}; m.u00i = f32x2{a.z, a.w};
  m.u01r = f32x2{b.x, b.y}; m.u01i = f32x2{b.z, b.w};
  m.u10r = f32x2{c.x, c.y}; m.u10i = f32x2{c.z, c.w};
  m.u11r = f32x2{d.x, d.y}; m.u11i = f32x2{d.z, d.w};
  return m;
}

struct Coef { f32x2 Ar, Ai, Br, Bi; };
__device__ __forceinline__ Coef mkcoef(const MatP& m, bool hi) {
  return { sel2(hi, m.u11r, m.u00r), sel2(hi, m.u11i, m.u00i),
           sel2(hi, m.u10r, m.u01r), sel2(hi, m.u10i, m.u01i) };
}
__device__ __forceinline__ Coef coefsel(bool c, const Coef& a, const Coef& b) {
  return { sel2(c, a.Ar, b.Ar), sel2(c, a.Ai, b.Ai),
           sel2(c, a.Br, b.Br), sel2(c, a.Bi, b.Bi) };
}
__device__ __forceinline__ MatP matsel(bool c, const MatP& a, const MatP& b) {
  MatP m;
  m.u00r = sel2(c, a.u00r, b.u00r); m.u00i = sel2(c, a.u00i, b.u00i);
  m.u01r = sel2(c, a.u01r, b.u01r); m.u01i = sel2(c, a.u01i, b.u01i);
  m.u10r = sel2(c, a.u10r, b.u10r); m.u10i = sel2(c, a.u10i, b.u10i);
  m.u11r = sel2(c, a.u11r, b.u11r); m.u11i = sel2(c, a.u11i, b.u11i);
  return m;
}

// ---- generic appliers (per-k matrix choice; cm compile-time) ----
__device__ __forceinline__ void xlane_apply(f32x2 (&s)[4], const int lm,
                                            const Coef c1, const Coef c0, const int cm) {
  #pragma unroll
  for (int k = 0; k < 4; ++k) {
    const Coef& c = (cm && (k & cm)) ? c1 : c0;
    const f32x2 p = shfl_fast(s[k], lm);
    s[k] = cmad(cmulp(c.Ar, c.Ai, s[k]), c.Br, c.Bi, p);
  }
}
__device__ __forceinline__ void local_apply(f32x2 (&s)[4], const int kb,
                                            const MatP m1, const MatP m0, const int cm) {
  const int tm = 1 << kb;
  #pragma unroll
  for (int k0 = 0; k0 < 4; ++k0) {
    if (k0 & tm) continue;
    const int k1 = k0 | tm;
    const MatP& m = (cm && (k0 & cm)) ? m1 : m0;
    const f32x2 a = s[k0], b = s[k1];
    s[k0] = cmad(cmulp(m.u00r, m.u00i, a), m.u01r, m.u01i, b);
    s[k1] = cmad(cmulp(m.u10r, m.u10i, a), m.u11r, m.u11i, b);
  }
}
__device__ __forceinline__ void xwave_apply(f32x2 (&s)[4], f32x2* lxb, const int wv,
                                            const int lane, const int tb,
                                            const Coef c1, const Coef c0, const int cm) {
  #pragma unroll
  for (int k = 0; k < 4; ++k) lxb[(wv * 4 + k) * 64 + lane] = s[k];
  __syncthreads();
  const int pw = wv ^ (1 << tb);
  #pragma unroll
  for (int k = 0; k < 4; ++k) {
    const Coef& c = (cm && (k & cm)) ? c1 : c0;
    const f32x2 p = lxb[(pw * 4 + k) * 64 + lane];
    s[k] = cmad(cmulp(c.Ar, c.Ai, s[k]), c.Br, c.Bi, p);
  }
}

// ---- single-gate applier (A0 = identity: keeps skip/I-fold fast paths) ----
__device__ __forceinline__ void apply_gate(f32x2 (&s)[4], f32x2* lxb, const int wv,
                                           const int lane, const MatP mIn,
                                           const int bt, const int bc) {
  MatP m = mIn;
  const f32x2 oner{1.f, 1.f}, zero{0.f, 0.f};
  int cm_reg = 0;
  bool fold = false, cl = true;
  if (bc >= 8)      { cl = ((wv >> (bc - 8)) & 1) != 0; fold = true; }
  else if (bc >= 6) { cm_reg = 1 << (bc - 6); }
  else if (bc >= 0) { cl = ((lane >> bc) & 1) != 0; fold = true; }

  if (bt >= 8) {
    const int tb = bt - 8;
    const bool hi = ((wv >> tb) & 1) != 0;
    Coef c = mkcoef(m, hi);
    if (fold) {
      c.Ar = sel2(cl, c.Ar, oner); c.Ai = sel2(cl, c.Ai, zero);
      c.Br = sel2(cl, c.Br, zero); c.Bi = sel2(cl, c.Bi, zero);
    }
    if (cm_reg) {
      // skip path: identity on non-ctrl regs
      #pragma unroll
      for (int k = 0; k < 4; ++k) lxb[(wv * 4 + k) * 64 + lane] = s[k];
      __syncthreads();
      const int pw = wv ^ (1 << tb);
      #pragma unroll
      for (int k = 0; k < 4; ++k) {
        if (!(k & cm_reg)) continue;
        const f32x2 p = lxb[(pw * 4 + k) * 64 + lane];
        s[k] = cmad(cmulp(c.Ar, c.Ai, s[k]), c.Br, c.Bi, p);
      }
    } else {
      xwave_apply(s, lxb, wv, lane, tb, c, c, 0);
    }
  } else if (bt >= 6) {
    if (fold) {
      m.u00r = sel2(cl, m.u00r, oner); m.u00i = sel2(cl, m.u00i, zero);
      m.u01r = sel2(cl, m.u01r, zero); m.u01i = sel2(cl, m.u01i, zero);
      m.u10r = sel2(cl, m.u10r, zero); m.u10i = sel2(cl, m.u10i, zero);
      m.u11r = sel2(cl, m.u11r, oner); m.u11i = sel2(cl, m.u11i, zero);
    }
    const int tm = 1 << (bt - 6);
    #pragma unroll
    for (int k0 = 0; k0 < 4; ++k0) {
      if (k0 & tm) continue;
      if (cm_reg && !(k0 & cm_reg)) continue;
      const int k1 = k0 | tm;
      const f32x2 a = s[k0], b = s[k1];
      s[k0] = cmad(cmulp(m.u00r, m.u00i, a), m.u01r, m.u01i, b);
      s[k1] = cmad(cmulp(m.u10r, m.u10i, a), m.u11r, m.u11i, b);
    }
  } else {
    const bool hi = ((lane >> bt) & 1) != 0;
    Coef c = mkcoef(m, hi);
    if (fold) {
      c.Ar = sel2(cl, c.Ar, oner); c.Ai = sel2(cl, c.Ai, zero);
      c.Br = sel2(cl, c.Br, zero); c.Bi = sel2(cl, c.Bi, zero);
    }
    const int lm = 1 << bt;
    #pragma unroll
    for (int k = 0; k < 4; ++k) {
      if (cm_reg && !(k & cm_reg)) continue;
      const f32x2 p = shfl_fast(s[k], lm);
      s[k] = cmad(cmulp(c.Ar, c.Ai, s[k]), c.Br, c.Bi, p);
    }
  }
}

// ---- fused pair-gate applier: ctrl=1 -> A1, ctrl=0 -> A0 (bc >= 0 always) ----
__device__ __forceinline__ void apply_gate2(f32x2 (&s)[4], f32x2* lxb, const int wv,
                                            const int lane, const MatP m1, const MatP m0,
                                            const int bt, const int bc) {
  int cm = 0; bool cl = true; bool lc = false;
  if (bc >= 8)      { cl = ((wv >> (bc - 8)) & 1) != 0; lc = true; }
  else if (bc >= 6) { cm = 1 << (bc - 6); }
  else              { cl = ((lane >> bc) & 1) != 0; lc = true; }

  if (bt >= 8) {
    const int tb = bt - 8;
    const bool hi = ((wv >> tb) & 1) != 0;
    const Coef c1 = mkcoef(m1, hi), c0 = mkcoef(m0, hi);
    if (lc) {
      const Coef cc = coefsel(cl, c1, c0);
      xwave_apply(s, lxb, wv, lane, tb, cc, cc, 0);
    } else {
      xwave_apply(s, lxb, wv, lane, tb, c1, c0, cm);
    }
  } else if (bt >= 6) {
    if (lc) {
      const MatP m = matsel(cl, m1, m0);
      local_apply(s, bt - 6, m, m, 0);
    } else {
      local_apply(s, bt - 6, m1, m0, cm);
    }
  } else {
    const int lm = 1 << bt;
    const bool hi = ((lane >> bt) & 1) != 0;
    const Coef c1 = mkcoef(m1, hi), c0 = mkcoef(m0, hi);
    if (lc) {
      const Coef cc = coefsel(cl, c1, c0);
      xlane_apply(s, lm, cc, cc, 0);
    } else {
      xlane_apply(s, lm, c1, c0, cm);
    }
  }
}

// Fused prep. Blocks <1024: build row n=blockIdx of U (4 waves, 4 regs/lane).
// Blocks >=1024: xconv (832 cols, packed cvt).
__global__ __launch_bounds__(256) void qprep(const float* __restrict__ prog,
                                             const float* __restrict__ x,
                                             _Float16* __restrict__ Wt,
                                             _Float16* __restrict__ Xh) {
  const int tid = threadIdx.x;
  if (blockIdx.x >= 1024) {
    const int t = (blockIdx.x - 1024) * 256 + tid;
    const int b = t >> 7;
    const int j = (t & 127) * 8;
    if (j >= 832) return;
    union { fp16x2 h2[4]; f16x8 h8; } u;
    if (j < 784) {
      const float4* p = reinterpret_cast<const float4*>(x + (size_t)b * 784 + j);
      const float4 v0 = p[0], v1 = p[1];
      u.h2[0] = __builtin_amdgcn_cvt_pkrtz(v0.x, v0.y);
      u.h2[1] = __builtin_amdgcn_cvt_pkrtz(v0.z, v0.w);
      u.h2[2] = __builtin_amdgcn_cvt_pkrtz(v1.x, v1.y);
      u.h2[3] = __builtin_amdgcn_cvt_pkrtz(v1.z, v1.w);
    } else {
      #pragma unroll
      for (int q = 0; q < 4; ++q) u.h2[q] = __builtin_amdgcn_cvt_pkrtz(0.f, 0.f);
    }
    *reinterpret_cast<f16x8*>(Xh + (size_t)b * 1024 + j) = u.h8;
    return;
  }

  // ---- build_W ----
  __shared__ f32x2 lx[2][1024];   // double-buffered exchange (16 KB)

  const int lane = tid & 63;
  const int wv = tid >> 6;
  const int n = blockIdx.x;

  f32x2 s[4];
  #pragma unroll
  for (int k = 0; k < 4; ++k) {
    const int j = (wv << 8) | (k << 6) | lane;
    s[k].x = (j == n) ? 1.f : 0.f;
    s[k].y = 0.f;
  }

  int p = 0, ph = 0;
  #pragma unroll
  for (int dd = 0; dd < 5; ++dd) {
    const int d = 4 - dd;
    if (d == 4) {
      apply_gate(s, &lx[ph & 1][0], wv, lane, ldmatG2(prog, p, 0), 9, -1);
      ++p; ++ph;
    }
    const int r = (d & 1) ? 3 : 1;
    #pragma unroll
    for (int ii = 0; ii < 10; ++ii) {
      const int i = 9 - ii;
      const int c = (i + r) % 10;
      const int bt = 9 - i, bc = 9 - c;
      const bool fused = (d <= 3) && fusable(d, i);
      if (fused) {
        apply_gate2(s, &lx[ph & 1][0], wv, lane,
                    ldmatG2(prog, p, 1), ldmatG2(prog, p, 0), bt, bc);
      } else {
        apply_gate(s, &lx[ph & 1][0], wv, lane, ldmatG2(prog, p, 0), bt, bc);
      }
      ++p; if (bt >= 8) ++ph;
    }
    #pragma unroll
    for (int ii = 0; ii < 10; ++ii) {
      const int i = 9 - ii;
      if (d >= 1 && fusable(d - 1, i)) continue;   // absorbed forward
      const int bt = 9 - i;
      apply_gate(s, &lx[ph & 1][0], wv, lane, ldmatG2(prog, p, 0), bt, -1);
      ++p; if (bt >= 8) ++ph;
    }
  }

  // psi = U^dagger e_n => U[n][j] = (s.x, -s.y)
  #pragma unroll
  for (int k = 0; k < 4; ++k) {
    const int j = (wv << 8) | (k << 6) | lane;
    Wt[(size_t)(2 * n) * 1024 + j] = (_Float16)s[k].x;
    Wt[(size_t)(2 * n + 1) * 1024 + j] = (_Float16)(-s[k].y);
  }
}

// ---------------- LDS-staged GEMM (unchanged from R11) ----------------
#define GZ_NSTEP 13

__device__ __forceinline__ void stage_tiles(const _Float16* __restrict__ gA,
                                            const _Float16* __restrict__ gB,
                                            _Float16* sA, _Float16* sB,
                                            int k0, int wv, int lane) {
  const int rIn = lane >> 3;
  const int colh = ((lane & 7) ^ rIn) * 8;
  #pragma unroll
  for (int c = 0; c < 2; ++c) {
    const int chunk = wv * 2 + c;
    const size_t grow = (size_t)(chunk * 8 + rIn) * 1024 + k0 + colh;
    auto* la = (__attribute__((address_space(3))) void*)(sA + chunk * 512 + lane * 8);
    __builtin_amdgcn_global_load_lds(
        (const __attribute__((address_space(1))) void*)(gA + grow), la, 16, 0, 0);
    auto* lb = (__attribute__((address_space(3))) void*)(sB + chunk * 512 + lane * 8);
    __builtin_amdgcn_global_load_lds(
        (const __attribute__((address_space(1))) void*)(gB + grow), lb, 16, 0, 0);
  }
}

__device__ __forceinline__ int lds_off(int row, int slot) {
  return row * 64 + ((slot ^ (row & 7)) * 8);
}

__global__ __launch_bounds__(512) void gemm_z(const _Float16* __restrict__ Xh,
                                              const _Float16* __restrict__ Wt,
                                              float* __restrict__ part, int B) {
  __shared__ _Float16 smA[2][128 * 64];
  __shared__ _Float16 smB[2][128 * 64];

  const int tid = threadIdx.x;
  const int lane = tid & 63;
  const int wv = tid >> 6;
  const int wm = wv >> 1;
  const int wn = wv & 1;
  const int row0 = blockIdx.x * 128;
  const int n0 = blockIdx.y * 128;

  const _Float16* gA = Xh + (size_t)row0 * 1024;
  const _Float16* gB = Wt + (size_t)n0 * 1024;

  const int lr = lane & 15;
  const int lq = lane >> 4;

  f32x4v acc[2][4];
  #pragma unroll
  for (int m = 0; m < 2; ++m)
    #pragma unroll
    for (int f = 0; f < 4; ++f) acc[m][f] = f32x4v{0.f, 0.f, 0.f, 0.f};

  stage_tiles(gA, gB, smA[0], smB[0], 0, wv, lane);
  __syncthreads();

  for (int t = 0; t < GZ_NSTEP; ++t) {
    const int cur = t & 1;
    if (t + 1 < GZ_NSTEP)
      stage_tiles(gA, gB, smA[cur ^ 1], smB[cur ^ 1], (t + 1) * 64, wv, lane);

    #pragma unroll
    for (int kk = 0; kk < 2; ++kk) {
      const int slot = kk * 4 + lq;
      f16x8 a[2], b[4];
      #pragma unroll
      for (int m = 0; m < 2; ++m) {
        const int row = wm * 32 + m * 16 + lr;
        a[m] = *reinterpret_cast<const f16x8*>(&smA[cur][lds_off(row, slot)]);
      }
      #pragma unroll
      for (int f = 0; f < 4; ++f) {
        const int row = wn * 64 + f * 16 + lr;
        b[f] = *reinterpret_cast<const f16x8*>(&smB[cur][lds_off(row, slot)]);
      }
      #pragma unroll
      for (int m = 0; m < 2; ++m)
        #pragma unroll
        for (int f = 0; f < 4; ++f)
          acc[m][f] = __builtin_amdgcn_mfma_f32_16x16x32_f16(a[m], b[f], acc[m][f], 0, 0, 0);
    }
    __syncthreads();
  }

  const int pp = blockIdx.y * 2 + wn;
  #pragma unroll
  for (int m = 0; m < 2; ++m) {
    f32x4v p = f32x4v{0.f, 0.f, 0.f, 0.f};
    #pragma unroll
    for (int f = 0; f < 4; ++f) p += acc[m][f] * acc[m][f];
    #pragma unroll
    for (int msk = 1; msk < 16; msk <<= 1) {
      p.x += __shfl_xor(p.x, msk, 64);
      p.y += __shfl_xor(p.y, msk, 64);
      p.z += __shfl_xor(p.z, msk, 64);
      p.w += __shfl_xor(p.w, msk, 64);
    }
    if (lr == 0) {
      const int rbase = row0 + wm * 32 + m * 16 + lq * 4;
      float* dst = part + (size_t)pp * B + rbase;
      dst[0] = p.x; dst[1] = p.y; dst[2] = p.z; dst[3] = p.w;
    }
  }
}

// ---- NLL ----
__global__ __launch_bounds__(256) void nll_part(const float* __restrict__ part,
                                                const int* __restrict__ y,
                                                float* __restrict__ out2, int B) {
  const int row = blockIdx.x * 256 + threadIdx.x;
  float q0 = 0.f, q1 = 0.f, nn = 0.f;
  #pragma unroll
  for (int pp = 0; pp < 32; ++pp) {
    const float P = part[(size_t)pp * B + row];
    q0 += (pp & 16) ? -P : P;
    q1 += (pp & 8) ? -P : P;
    nn += P;
  }
  const float z0 = q0 / nn, z1 = q1 / nn;
  const float mx = fmaxf(z0, z1);
  const float lse = mx + logf(expf(z0 - mx) + expf(z1 - mx));
  const float ly = (y[row] == 0) ? z0 : z1;
  float s = lse - ly;
  #pragma unroll
  for (int msk = 1; msk < 64; msk <<= 1) s += __shfl_xor(s, msk, 64);
  __shared__ float red[4];
  if ((threadIdx.x & 63) == 0) red[threadIdx.x >> 6] = s;
  __syncthreads();
  if (threadIdx.x == 0) out2[blockIdx.x] = red[0] + red[1] + red[2] + red[3];
}

__global__ void nll_final(const float* __restrict__ out2, float* __restrict__ out,
                          int nblk, float scale) {
  const int t = threadIdx.x;
  float s = (t < nblk) ? out2[t] : 0.f;
  #pragma unroll
  for (int msk = 1; msk < 64; msk <<= 1) s += __shfl_xor(s, msk, 64);
  if (t == 0) out[0] = s * scale;
}

} // namespace

extern "C" void kernel_launch(void* const* d_in, const int* in_sizes, int n_in,
                              void* d_out, int out_size, void* d_ws, size_t ws_size,
                              hipStream_t stream) {
  const float* x  = (const float*)d_in[0];
  const int*   y  = (const int*)d_in[1];
  const float* w  = (const float*)d_in[2];
  const float* w1 = (const float*)d_in[3];
  const float* w2 = (const float*)d_in[4];
  float* out = (float*)d_out;

  const int B = in_sizes[0] / 784;      // 8192

  char* ws = (char*)d_ws;
  _Float16* Wt   = (_Float16*)ws;                                // 4 MB
  _Float16* Xh   = (_Float16*)(ws + (size_t)2048 * 1024 * 2);    // 16 MB
  float*    part = (float*)(ws + (size_t)2048 * 1024 * 2 + (size_t)B * 1024 * 2);
  float*    out2 = part + (size_t)32 * B;
  float*    prog = out2 + 64;           // 69*32 floats

  make_prog<<<1, 128, 0, stream>>>(w, w1, w2, prog);
  qprep<<<1024 + (B * 128) / 256, 256, 0, stream>>>(prog, x, Wt, Xh);
  gemm_z<<<dim3(B / 128, 16), 512, 0, stream>>>(Xh, Wt, part, B);
  nll_part<<<B / 256, 256, 0, stream>>>(part, y, out2, B);
  nll_final<<<1, 64, 0, stream>>>(out2, out, B / 256, 1.0f / (float)B);
}

// Round 16
// 78.790 us; speedup vs baseline: 1.1302x; 1.1094x over previous
//
#include <hip/hip_runtime.h>

// CCQC classifier, GEMM formulation. R16: variant-table gates (no folding).
//   make_prog precomputes per-op ALL coefficient variants (hi x ctrl, with
//   identity baked in for unfused ctrl gates, A0/A1 for fused pairs) in
//   packed {re,re,-im,im} form -> 64 floats/op. qprep computes a 2-bit
//   variant index from lane/wave/k bits and loads its coefs directly --
//   eliminating ~24-48 v_cndmask per gate (R15: VALUBusy 58%, 4x pure math).
//   Gate set: R15's fused 69-op reversed-adjoint program (101 -> 69).
//   qprep blocks >=1024: xconv fp32 -> fp16 (832 cols).
//   gemm_z: 128x128 tile BK=64, 8 waves, global_load_lds + XOR swizzle,
//   fused |psi|^2 epilogue -> 32 chunk partials. nll_part + nll_final.

namespace {

typedef float f32x2 __attribute__((ext_vector_type(2)));
typedef __fp16 fp16x2 __attribute__((ext_vector_type(2)));
typedef _Float16 f16x8 __attribute__((ext_vector_type(8)));
typedef float f32x4v __attribute__((ext_vector_type(4)));

// ---- packed dual-f32 ops (VOP3P), untied operands ----
__device__ __forceinline__ f32x2 pk_mul(f32x2 a, f32x2 b) {
  f32x2 d;
  asm("v_pk_mul_f32 %0, %1, %2" : "=v"(d) : "v"(a), "v"(b));
  return d;
}
__device__ __forceinline__ f32x2 pk_fma(f32x2 a, f32x2 b, f32x2 c) {
  f32x2 d;
  asm("v_pk_fma_f32 %0, %1, %2, %3" : "=v"(d) : "v"(a), "v"(b), "v"(c));
  return d;
}
__device__ __forceinline__ f32x2 pk_fma_swap1(f32x2 a, f32x2 b, f32x2 c) {
  f32x2 d;
  asm("v_pk_fma_f32 %0, %1, %2, %3 op_sel:[0,1,0] op_sel_hi:[1,0,1]"
      : "=v"(d) : "v"(a), "v"(b), "v"(c));
  return d;
}
__device__ __forceinline__ f32x2 cmulp(f32x2 cr2, f32x2 ci2, f32x2 v) {
  return pk_fma_swap1(ci2, v, pk_mul(cr2, v));
}
__device__ __forceinline__ f32x2 cmad(f32x2 acc, f32x2 cr2, f32x2 ci2, f32x2 v) {
  return pk_fma_swap1(ci2, v, pk_fma(cr2, v, acc));
}

__device__ __forceinline__ f32x2 shfl_xor2(f32x2 v, int lm) {
  f32x2 r;
  r.x = __shfl_xor(v.x, lm, 64);
  r.y = __shfl_xor(v.y, lm, 64);
  return r;
}
template <int CTRL>
__device__ __forceinline__ f32x2 dpp_xor2(f32x2 v) {
  f32x2 r;
  const int ix = __builtin_bit_cast(int, v.x);
  const int iy = __builtin_bit_cast(int, v.y);
  r.x = __builtin_bit_cast(float,
      __builtin_amdgcn_update_dpp(0, ix, CTRL, 0xF, 0xF, true));
  r.y = __builtin_bit_cast(float,
      __builtin_amdgcn_update_dpp(0, iy, CTRL, 0xF, 0xF, true));
  return r;
}
__device__ __forceinline__ f32x2 shfl_fast(f32x2 v, const int lm) {
  if (lm == 1) return dpp_xor2<0xB1>(v);
  if (lm == 2) return dpp_xor2<0x4E>(v);
  return shfl_xor2(v, lm);
}

struct c2 { float r, i; };
struct m2c { c2 a00, a01, a10, a11; };

__device__ __forceinline__ c2 cmul(c2 x, c2 y) { return {x.r*y.r - x.i*y.i, x.r*y.i + x.i*y.r}; }
__device__ __forceinline__ c2 cadd(c2 x, c2 y) { return {x.r + y.r, x.i + y.i}; }
__device__ __forceinline__ c2 conjc(c2 a) { return {a.r, -a.i}; }
__device__ __forceinline__ m2c mmul(m2c A, m2c B) {
  m2c C;
  C.a00 = cadd(cmul(A.a00, B.a00), cmul(A.a01, B.a10));
  C.a01 = cadd(cmul(A.a00, B.a01), cmul(A.a01, B.a11));
  C.a10 = cadd(cmul(A.a10, B.a00), cmul(A.a11, B.a10));
  C.a11 = cadd(cmul(A.a10, B.a01), cmul(A.a11, B.a11));
  return C;
}
__device__ __forceinline__ m2c madj(m2c U) {
  return { conjc(U.a00), conjc(U.a10), conjc(U.a01), conjc(U.a11) };
}
__device__ __forceinline__ m2c mrx(float t) {
  float c = cosf(0.5f * t), s = sinf(0.5f * t);
  return { {c, 0.f}, {0.f, -s}, {0.f, -s}, {c, 0.f} };
}
__device__ __forceinline__ m2c mrz(float t) {
  float c = cosf(0.5f * t), s = sinf(0.5f * t);
  return { {c, -s}, {0.f, 0.f}, {0.f, 0.f}, {c, s} };
}

// fusable(d,i): CU[i](d) absorbs U1[i](d+1). r(d)=1 (d even): i>=1; r=3: i>=3.
__device__ __forceinline__ bool fusable(int d, int i) {
  return (d & 1) ? (i >= 3) : (i >= 1);
}

// 69-op program, 64 floats/op.
//  coef-form ops (bt>=8 or bt<6): 4 variants v = hi + 2*c at o[v*8]:
//    {cA.r, cA.r, -cA.i, cA.i, cB.r, cB.r, -cB.i, cB.i},
//    cA = hi? M.a11 : M.a00, cB = hi? M.a10 : M.a01, M = c? M1 : M0.
//  matrix-form ops (bt in {6,7}): M0 packed16 at o[0], M1 packed16 at o[16].
//  M0/M1: unfused no-ctrl: both = adj; unfused ctrl: {I, adj(CU)};
//  fused: {adj(U1), adj(CU)*adj(U1)}.
__global__ void make_prog(const float* __restrict__ w, const float* __restrict__ w1,
                          const float* __restrict__ w2, float* __restrict__ prog) {
  const int t = threadIdx.x;
  int kind = -1, od = 0, oi = 0, p = 0;
  for (int dd = 0; dd < 5; ++dd) {
    const int d = 4 - dd;
    if (d == 4) { if (p == t) kind = 0; ++p; }
    for (int ii = 0; ii < 10; ++ii) {
      const int i = 9 - ii;
      if (p == t) { kind = (d <= 3 && fusable(d, i)) ? 2 : 1; od = d; oi = i; }
      ++p;
    }
    for (int ii = 0; ii < 10; ++ii) {
      const int i = 9 - ii;
      if (d >= 1 && fusable(d - 1, i)) continue;
      if (p == t) { kind = 3; od = d; oi = i; }
      ++p;
    }
  }
  if (kind < 0) return;

  auto u1mat = [&](int d, int i) -> m2c {
    const float* pw = w + (d * 10 + i) * 5;
    m2c U = mmul(mrx(pw[2]), mmul(mrz(pw[1]), mrx(pw[0])));
    if (i == 0 && d > 0) {
      m2c U0 = mmul(mrz(w2[d - 1]), mrx(w1[d - 1]));
      U = mmul(U, U0);
    }
    return U;
  };
  auto cumat = [&](int d, int i) -> m2c {
    const float* pw = w + (d * 10 + i) * 5;
    return mmul(mrx(pw[4]), mrz(pw[3]));
  };

  m2c M0{}, M1{};
  int bt = 9;
  if (kind == 0) {
    M0 = madj(mmul(mrz(w2[4]), mrx(w1[4]))); M1 = M0; bt = 9;
  } else if (kind == 1) {
    M1 = madj(cumat(od, oi));
    M0 = m2c{ {1.f, 0.f}, {0.f, 0.f}, {0.f, 0.f}, {1.f, 0.f} };
    bt = 9 - oi;
  } else if (kind == 2) {
    m2c V1 = madj(u1mat(od + 1, oi));
    m2c VC = madj(cumat(od, oi));
    M0 = V1; M1 = mmul(VC, V1);
    bt = 9 - oi;
  } else {
    M0 = madj(u1mat(od, oi)); M1 = M0; bt = 9 - oi;
  }

  float* o = prog + t * 64;
  if (bt >= 8 || bt < 6) {
    #pragma unroll
    for (int v = 0; v < 4; ++v) {
      const bool hi = (v & 1) != 0;
      const m2c& M = (v >> 1) ? M1 : M0;
      const c2 cA = hi ? M.a11 : M.a00;
      const c2 cB = hi ? M.a10 : M.a01;
      o[v*8+0] = cA.r; o[v*8+1] = cA.r; o[v*8+2] = -cA.i; o[v*8+3] = cA.i;
      o[v*8+4] = cB.r; o[v*8+5] = cB.r; o[v*8+6] = -cB.i; o[v*8+7] = cB.i;
    }
  } else {
    const m2c* Ms[2] = {&M0, &M1};
    #pragma unroll
    for (int c = 0; c < 2; ++c) {
      const c2 e[4] = {Ms[c]->a00, Ms[c]->a01, Ms[c]->a10, Ms[c]->a11};
      #pragma unroll
      for (int q = 0; q < 4; ++q) {
        o[c*16 + q*4 + 0] = e[q].r; o[c*16 + q*4 + 1] = e[q].r;
        o[c*16 + q*4 + 2] = -e[q].i; o[c*16 + q*4 + 3] = e[q].i;
      }
    }
  }
}

struct CoefP { f32x2 Ar, Ai, Br, Bi; };
__device__ __forceinline__ CoefP ldcoef(const float* __restrict__ g, int v) {
  const float4* p = reinterpret_cast<const float4*>(g + v * 8);
  const float4 a = p[0], b = p[1];
  return { f32x2{a.x, a.y}, f32x2{a.z, a.w}, f32x2{b.x, b.y}, f32x2{b.z, b.w} };
}
struct MatP { f32x2 u00r, u00i, u01r, u01i, u10r, u10i, u11r, u11i; };
__device__ __forceinline__ MatP ldmat16(const float* __restrict__ g, int c) {
  const float4* p = reinterpret_cast<const float4*>(g + c * 16);
  const float4 a = p[0], b = p[1], cc = p[2], d = p[3];
  MatP m;
  m.u00r = f32x2{a.x, a.y};  m.u00i = f32x2{a.z, a.w};
  m.u01r = f32x2{b.x, b.y};  m.u01i = f32x2{b.z, b.w};
  m.u10r = f32x2{cc.x, cc.y}; m.u10i = f32x2{cc.z, cc.w};
  m.u11r = f32x2{d.x, d.y};  m.u11i = f32x2{d.z, d.w};
  return m;
}
__device__ __forceinline__ f32x2 capply(const CoefP& c, f32x2 own, f32x2 par) {
  return cmad(cmulp(c.Ar, c.Ai, own), c.Br, c.Bi, par);
}

// One program op. bt/bc compile-time after full unroll.
__device__ __forceinline__ void apply_op(f32x2 (&s)[4], f32x2* lxb, const int wv,
                                         const int lane, const float* __restrict__ g,
                                         const int bt, const int bc) {
  if (bt >= 8) {
    // cross-wave exchange: store, 1 barrier, read partner, apply
    const int tb = bt - 8;
    const int hi = (wv >> tb) & 1;
    #pragma unroll
    for (int k = 0; k < 4; ++k) lxb[(wv * 4 + k) * 64 + lane] = s[k];
    __syncthreads();
    const int pw = wv ^ (1 << tb);
    f32x2 pp[4];
    #pragma unroll
    for (int k = 0; k < 4; ++k) pp[k] = lxb[(pw * 4 + k) * 64 + lane];
    if (bc >= 8) {
      const int c = (wv >> (bc - 8)) & 1;
      const CoefP cf = ldcoef(g, hi + 2 * c);
      #pragma unroll
      for (int k = 0; k < 4; ++k) s[k] = capply(cf, s[k], pp[k]);
    } else if (bc >= 6) {
      const int cb = bc - 6;
      const CoefP c0 = ldcoef(g, hi), c1 = ldcoef(g, hi + 2);
      #pragma unroll
      for (int k = 0; k < 4; ++k)
        s[k] = capply(((k >> cb) & 1) ? c1 : c0, s[k], pp[k]);
    } else if (bc >= 0) {
      const int c = (lane >> bc) & 1;
      const CoefP cf = ldcoef(g, hi + 2 * c);
      #pragma unroll
      for (int k = 0; k < 4; ++k) s[k] = capply(cf, s[k], pp[k]);
    } else {
      const CoefP cf = ldcoef(g, hi);
      #pragma unroll
      for (int k = 0; k < 4; ++k) s[k] = capply(cf, s[k], pp[k]);
    }
  } else if (bt >= 6) {
    const int tm = 1 << (bt - 6);
    if (bc >= 6 && bc < 8) {
      const int cb = bc - 6;
      const MatP m0 = ldmat16(g, 0), m1 = ldmat16(g, 1);
      #pragma unroll
      for (int k0 = 0; k0 < 4; ++k0) {
        if (k0 & tm) continue;
        const int k1 = k0 | tm;
        const MatP& m = ((k0 >> cb) & 1) ? m1 : m0;
        const f32x2 a = s[k0], b = s[k1];
        s[k0] = cmad(cmulp(m.u00r, m.u00i, a), m.u01r, m.u01i, b);
        s[k1] = cmad(cmulp(m.u10r, m.u10i, a), m.u11r, m.u11i, b);
      }
    } else {
      int c = 0;
      if (bc >= 8)      c = (wv >> (bc - 8)) & 1;
      else if (bc >= 0) c = (lane >> bc) & 1;
      const MatP m = ldmat16(g, c);
      #pragma unroll
      for (int k0 = 0; k0 < 4; ++k0) {
        if (k0 & tm) continue;
        const int k1 = k0 | tm;
        const f32x2 a = s[k0], b = s[k1];
        s[k0] = cmad(cmulp(m.u00r, m.u00i, a), m.u01r, m.u01i, b);
        s[k1] = cmad(cmulp(m.u10r, m.u10i, a), m.u11r, m.u11i, b);
      }
    }
  } else {
    const int lm = 1 << bt;
    const int hi = (lane >> bt) & 1;
    if (bc >= 6 && bc < 8) {
      const int cb = bc - 6;
      const CoefP c0 = ldcoef(g, hi), c1 = ldcoef(g, hi + 2);
      #pragma unroll
      for (int k = 0; k < 4; ++k) {
        const f32x2 p = shfl_fast(s[k], lm);
        s[k] = capply(((k >> cb) & 1) ? c1 : c0, s[k], p);
      }
    } else {
      int c = 1;
      if (bc >= 8)      c = (wv >> (bc - 8)) & 1;
      else if (bc >= 0) c = (lane >> bc) & 1;
      const CoefP cf = ldcoef(g, (bc >= 0) ? (hi + 2 * c) : hi);
      #pragma unroll
      for (int k = 0; k < 4; ++k) {
        const f32x2 p = shfl_fast(s[k], lm);
        s[k] = capply(cf, s[k], p);
      }
    }
  }
}

// Fused prep. Blocks <1024: build row n=blockIdx of U (4 waves, 4 regs/lane).
// Blocks >=1024: xconv (832 cols, packed cvt).
__global__ __launch_bounds__(256) void qprep(const float* __restrict__ prog,
                                             const float* __restrict__ x,
                                             _Float16* __restrict__ Wt,
                                             _Float16* __restrict__ Xh) {
  const int tid = threadIdx.x;
  if (blockIdx.x >= 1024) {
    const int t = (blockIdx.x - 1024) * 256 + tid;
    const int b = t >> 7;
    const int j = (t & 127) * 8;
    if (j >= 832) return;
    union { fp16x2 h2[4]; f16x8 h8; } u;
    if (j < 784) {
      const float4* p = reinterpret_cast<const float4*>(x + (size_t)b * 784 + j);
      const float4 v0 = p[0], v1 = p[1];
      u.h2[0] = __builtin_amdgcn_cvt_pkrtz(v0.x, v0.y);
      u.h2[1] = __builtin_amdgcn_cvt_pkrtz(v0.z, v0.w);
      u.h2[2] = __builtin_amdgcn_cvt_pkrtz(v1.x, v1.y);
      u.h2[3] = __builtin_amdgcn_cvt_pkrtz(v1.z, v1.w);
    } else {
      #pragma unroll
      for (int q = 0; q < 4; ++q) u.h2[q] = __builtin_amdgcn_cvt_pkrtz(0.f, 0.f);
    }
    *reinterpret_cast<f16x8*>(Xh + (size_t)b * 1024 + j) = u.h8;
    return;
  }

  // ---- build_W ----
  __shared__ f32x2 lx[2][1024];   // double-buffered exchange (16 KB)

  const int lane = tid & 63;
  const int wv = tid >> 6;
  const int n = blockIdx.x;

  f32x2 s[4];
  #pragma unroll
  for (int k = 0; k < 4; ++k) {
    const int j = (wv << 8) | (k << 6) | lane;
    s[k].x = (j == n) ? 1.f : 0.f;
    s[k].y = 0.f;
  }

  int p = 0, ph = 0;
  #pragma unroll
  for (int dd = 0; dd < 5; ++dd) {
    const int d = 4 - dd;
    if (d == 4) {
      apply_op(s, &lx[ph & 1][0], wv, lane, prog + p * 64, 9, -1);
      ++p; ++ph;
    }
    const int r = (d & 1) ? 3 : 1;
    #pragma unroll
    for (int ii = 0; ii < 10; ++ii) {
      const int i = 9 - ii;
      const int c = (i + r) % 10;
      const int bt = 9 - i, bc = 9 - c;
      apply_op(s, &lx[ph & 1][0], wv, lane, prog + p * 64, bt, bc);
      ++p; if (bt >= 8) ++ph;
    }
    #pragma unroll
    for (int ii = 0; ii < 10; ++ii) {
      const int i = 9 - ii;
      if (d >= 1 && fusable(d - 1, i)) continue;   // absorbed forward
      const int bt = 9 - i;
      apply_op(s, &lx[ph & 1][0], wv, lane, prog + p * 64, bt, -1);
      ++p; if (bt >= 8) ++ph;
    }
  }

  // psi = U^dagger e_n => U[n][j] = (s.x, -s.y)
  #pragma unroll
  for (int k = 0; k < 4; ++k) {
    const int j = (wv << 8) | (k << 6) | lane;
    Wt[(size_t)(2 * n) * 1024 + j] = (_Float16)s[k].x;
    Wt[(size_t)(2 * n + 1) * 1024 + j] = (_Float16)(-s[k].y);
  }
}

// ---------------- LDS-staged GEMM (unchanged from R11) ----------------
#define GZ_NSTEP 13

__device__ __forceinline__ void stage_tiles(const _Float16* __restrict__ gA,
                                            const _Float16* __restrict__ gB,
                                            _Float16* sA, _Float16* sB,
                                            int k0, int wv, int lane) {
  const int rIn = lane >> 3;
  const int colh = ((lane & 7) ^ rIn) * 8;
  #pragma unroll
  for (int c = 0; c < 2; ++c) {
    const int chunk = wv * 2 + c;
    const size_t grow = (size_t)(chunk * 8 + rIn) * 1024 + k0 + colh;
    auto* la = (__attribute__((address_space(3))) void*)(sA + chunk * 512 + lane * 8);
    __builtin_amdgcn_global_load_lds(
        (const __attribute__((address_space(1))) void*)(gA + grow), la, 16, 0, 0);
    auto* lb = (__attribute__((address_space(3))) void*)(sB + chunk * 512 + lane * 8);
    __builtin_amdgcn_global_load_lds(
        (const __attribute__((address_space(1))) void*)(gB + grow), lb, 16, 0, 0);
  }
}

__device__ __forceinline__ int lds_off(int row, int slot) {
  return row * 64 + ((slot ^ (row & 7)) * 8);
}

__global__ __launch_bounds__(512) void gemm_z(const _Float16* __restrict__ Xh,
                                              const _Float16* __restrict__ Wt,
                                              float* __restrict__ part, int B) {
  __shared__ _Float16 smA[2][128 * 64];
  __shared__ _Float16 smB[2][128 * 64];

  const int tid = threadIdx.x;
  const int lane = tid & 63;
  const int wv = tid >> 6;
  const int wm = wv >> 1;
  const int wn = wv & 1;
  const int row0 = blockIdx.x * 128;
  const int n0 = blockIdx.y * 128;

  const _Float16* gA = Xh + (size_t)row0 * 1024;
  const _Float16* gB = Wt + (size_t)n0 * 1024;

  const int lr = lane & 15;
  const int lq = lane >> 4;

  f32x4v acc[2][4];
  #pragma unroll
  for (int m = 0; m < 2; ++m)
    #pragma unroll
    for (int f = 0; f < 4; ++f) acc[m][f] = f32x4v{0.f, 0.f, 0.f, 0.f};

  stage_tiles(gA, gB, smA[0], smB[0], 0, wv, lane);
  __syncthreads();

  for (int t = 0; t < GZ_NSTEP; ++t) {
    const int cur = t & 1;
    if (t + 1 < GZ_NSTEP)
      stage_tiles(gA, gB, smA[cur ^ 1], smB[cur ^ 1], (t + 1) * 64, wv, lane);

    #pragma unroll
    for (int kk = 0; kk < 2; ++kk) {
      const int slot = kk * 4 + lq;
      f16x8 a[2], b[4];
      #pragma unroll
      for (int m = 0; m < 2; ++m) {
        const int row = wm * 32 + m * 16 + lr;
        a[m] = *reinterpret_cast<const f16x8*>(&smA[cur][lds_off(row, slot)]);
      }
      #pragma unroll
      for (int f = 0; f < 4; ++f) {
        const int row = wn * 64 + f * 16 + lr;
        b[f] = *reinterpret_cast<const f16x8*>(&smB[cur][lds_off(row, slot)]);
      }
      #pragma unroll
      for (int m = 0; m < 2; ++m)
        #pragma unroll
        for (int f = 0; f < 4; ++f)
          acc[m][f] = __builtin_amdgcn_mfma_f32_16x16x32_f16(a[m], b[f], acc[m][f], 0, 0, 0);
    }
    __syncthreads();
  }

  const int pp = blockIdx.y * 2 + wn;
  #pragma unroll
  for (int m = 0; m < 2; ++m) {
    f32x4v p = f32x4v{0.f, 0.f, 0.f, 0.f};
    #pragma unroll
    for (int f = 0; f < 4; ++f) p += acc[m][f] * acc[m][f];
    #pragma unroll
    for (int msk = 1; msk < 16; msk <<= 1) {
      p.x += __shfl_xor(p.x, msk, 64);
      p.y += __shfl_xor(p.y, msk, 64);
      p.z += __shfl_xor(p.z, msk, 64);
      p.w += __shfl_xor(p.w, msk, 64);
    }
    if (lr == 0) {
      const int rbase = row0 + wm * 32 + m * 16 + lq * 4;
      float* dst = part + (size_t)pp * B + rbase;
      dst[0] = p.x; dst[1] = p.y; dst[2] = p.z; dst[3] = p.w;
    }
  }
}

// ---- NLL ----
__global__ __launch_bounds__(256) void nll_part(const float* __restrict__ part,
                                                const int* __restrict__ y,
                                                float* __restrict__ out2, int B) {
  const int row = blockIdx.x * 256 + threadIdx.x;
  float q0 = 0.f, q1 = 0.f, nn = 0.f;
  #pragma unroll
  for (int pp = 0; pp < 32; ++pp) {
    const float P = part[(size_t)pp * B + row];
    q0 += (pp & 16) ? -P : P;
    q1 += (pp & 8) ? -P : P;
    nn += P;
  }
  const float z0 = q0 / nn, z1 = q1 / nn;
  const float mx = fmaxf(z0, z1);
  const float lse = mx + logf(expf(z0 - mx) + expf(z1 - mx));
  const float ly = (y[row] == 0) ? z0 : z1;
  float s = lse - ly;
  #pragma unroll
  for (int msk = 1; msk < 64; msk <<= 1) s += __shfl_xor(s, msk, 64);
  __shared__ float red[4];
  if ((threadIdx.x & 63) == 0) red[threadIdx.x >> 6] = s;
  __syncthreads();
  if (threadIdx.x == 0) out2[blockIdx.x] = red[0] + red[1] + red[2] + red[3];
}

__global__ void nll_final(const float* __restrict__ out2, float* __restrict__ out,
                          int nblk, float scale) {
  const int t = threadIdx.x;
  float s = (t < nblk) ? out2[t] : 0.f;
  #pragma unroll
  for (int msk = 1; msk < 64; msk <<= 1) s += __shfl_xor(s, msk, 64);
  if (t == 0) out[0] = s * scale;
}

} // namespace

extern "C" void kernel_launch(void* const* d_in, const int* in_sizes, int n_in,
                              void* d_out, int out_size, void* d_ws, size_t ws_size,
                              hipStream_t stream) {
  const float* x  = (const float*)d_in[0];
  const int*   y  = (const int*)d_in[1];
  const float* w  = (const float*)d_in[2];
  const float* w1 = (const float*)d_in[3];
  const float* w2 = (const float*)d_in[4];
  float* out = (float*)d_out;

  const int B = in_sizes[0] / 784;      // 8192

  char* ws = (char*)d_ws;
  _Float16* Wt   = (_Float16*)ws;                                // 4 MB
  _Float16* Xh   = (_Float16*)(ws + (size_t)2048 * 1024 * 2);    // 16 MB
  float*    part = (float*)(ws + (size_t)2048 * 1024 * 2 + (size_t)B * 1024 * 2);
  float*    out2 = part + (size_t)32 * B;
  float*    prog = out2 + 64;           // 69*64 floats

  make_prog<<<1, 128, 0, stream>>>(w, w1, w2, prog);
  qprep<<<1024 + (B * 128) / 256, 256, 0, stream>>>(prog, x, Wt, Xh);
  gemm_z<<<dim3(B / 128, 16), 512, 0, stream>>>(Xh, Wt, part, B);
  nll_part<<<B / 256, 256, 0, stream>>>(part, y, out2, B);
  nll_final<<<1, 64, 0, stream>>>(out2, out, B / 256, 1.0f / (float)B);
}

// Round 17
// 78.261 us; speedup vs baseline: 1.1378x; 1.0068x over previous
//
#include <hip/hip_runtime.h>

// CCQC classifier, GEMM formulation. R17: 2 states per build block (ILP fix).
//   R16 analysis: build chain is latency-bound (69 dependent ops x ~275cy,
//   4-wide ILP). Batch 2 basis states per block: coefficient loads amortized,
//   8 independent cmad streams, 512 blocks (2/CU), half the barrier-waits.
//   Program: R15/16's fused 69-op reversed-adjoint variant-table form.
//   qprep blocks >=512: xconv fp32 -> fp16 (832 cols).
//   gemm_z: 128x128 tile BK=64, 8 waves, global_load_lds + XOR swizzle,
//   fused |psi|^2 epilogue -> 32 chunk partials. nll_part + nll_final.

namespace {

typedef float f32x2 __attribute__((ext_vector_type(2)));
typedef __fp16 fp16x2 __attribute__((ext_vector_type(2)));
typedef _Float16 f16x8 __attribute__((ext_vector_type(8)));
typedef float f32x4v __attribute__((ext_vector_type(4)));

// ---- packed dual-f32 ops (VOP3P), untied operands ----
__device__ __forceinline__ f32x2 pk_mul(f32x2 a, f32x2 b) {
  f32x2 d;
  asm("v_pk_mul_f32 %0, %1, %2" : "=v"(d) : "v"(a), "v"(b));
  return d;
}
__device__ __forceinline__ f32x2 pk_fma(f32x2 a, f32x2 b, f32x2 c) {
  f32x2 d;
  asm("v_pk_fma_f32 %0, %1, %2, %3" : "=v"(d) : "v"(a), "v"(b), "v"(c));
  return d;
}
__device__ __forceinline__ f32x2 pk_fma_swap1(f32x2 a, f32x2 b, f32x2 c) {
  f32x2 d;
  asm("v_pk_fma_f32 %0, %1, %2, %3 op_sel:[0,1,0] op_sel_hi:[1,0,1]"
      : "=v"(d) : "v"(a), "v"(b), "v"(c));
  return d;
}
__device__ __forceinline__ f32x2 cmulp(f32x2 cr2, f32x2 ci2, f32x2 v) {
  return pk_fma_swap1(ci2, v, pk_mul(cr2, v));
}
__device__ __forceinline__ f32x2 cmad(f32x2 acc, f32x2 cr2, f32x2 ci2, f32x2 v) {
  return pk_fma_swap1(ci2, v, pk_fma(cr2, v, acc));
}

__device__ __forceinline__ f32x2 shfl_xor2(f32x2 v, int lm) {
  f32x2 r;
  r.x = __shfl_xor(v.x, lm, 64);
  r.y = __shfl_xor(v.y, lm, 64);
  return r;
}
template <int CTRL>
__device__ __forceinline__ f32x2 dpp_xor2(f32x2 v) {
  f32x2 r;
  const int ix = __builtin_bit_cast(int, v.x);
  const int iy = __builtin_bit_cast(int, v.y);
  r.x = __builtin_bit_cast(float,
      __builtin_amdgcn_update_dpp(0, ix, CTRL, 0xF, 0xF, true));
  r.y = __builtin_bit_cast(float,
      __builtin_amdgcn_update_dpp(0, iy, CTRL, 0xF, 0xF, true));
  return r;
}
__device__ __forceinline__ f32x2 shfl_fast(f32x2 v, const int lm) {
  if (lm == 1) return dpp_xor2<0xB1>(v);
  if (lm == 2) return dpp_xor2<0x4E>(v);
  return shfl_xor2(v, lm);
}

struct c2 { float r, i; };
struct m2c { c2 a00, a01, a10, a11; };

__device__ __forceinline__ c2 cmul(c2 x, c2 y) { return {x.r*y.r - x.i*y.i, x.r*y.i + x.i*y.r}; }
__device__ __forceinline__ c2 cadd(c2 x, c2 y) { return {x.r + y.r, x.i + y.i}; }
__device__ __forceinline__ c2 conjc(c2 a) { return {a.r, -a.i}; }
__device__ __forceinline__ m2c mmul(m2c A, m2c B) {
  m2c C;
  C.a00 = cadd(cmul(A.a00, B.a00), cmul(A.a01, B.a10));
  C.a01 = cadd(cmul(A.a00, B.a01), cmul(A.a01, B.a11));
  C.a10 = cadd(cmul(A.a10, B.a00), cmul(A.a11, B.a10));
  C.a11 = cadd(cmul(A.a10, B.a01), cmul(A.a11, B.a11));
  return C;
}
__device__ __forceinline__ m2c madj(m2c U) {
  return { conjc(U.a00), conjc(U.a10), conjc(U.a01), conjc(U.a11) };
}
__device__ __forceinline__ m2c mrx(float t) {
  float c = cosf(0.5f * t), s = sinf(0.5f * t);
  return { {c, 0.f}, {0.f, -s}, {0.f, -s}, {c, 0.f} };
}
__device__ __forceinline__ m2c mrz(float t) {
  float c = cosf(0.5f * t), s = sinf(0.5f * t);
  return { {c, -s}, {0.f, 0.f}, {0.f, 0.f}, {c, s} };
}

// fusable(d,i): CU[i](d) absorbs U1[i](d+1). r(d)=1 (d even): i>=1; r=3: i>=3.
__device__ __forceinline__ bool fusable(int d, int i) {
  return (d & 1) ? (i >= 3) : (i >= 1);
}

// 69-op program, 64 floats/op (variant-table form; see R16 header comment).
__global__ void make_prog(const float* __restrict__ w, const float* __restrict__ w1,
                          const float* __restrict__ w2, float* __restrict__ prog) {
  const int t = threadIdx.x;
  int kind = -1, od = 0, oi = 0, p = 0;
  for (int dd = 0; dd < 5; ++dd) {
    const int d = 4 - dd;
    if (d == 4) { if (p == t) kind = 0; ++p; }
    for (int ii = 0; ii < 10; ++ii) {
      const int i = 9 - ii;
      if (p == t) { kind = (d <= 3 && fusable(d, i)) ? 2 : 1; od = d; oi = i; }
      ++p;
    }
    for (int ii = 0; ii < 10; ++ii) {
      const int i = 9 - ii;
      if (d >= 1 && fusable(d - 1, i)) continue;
      if (p == t) { kind = 3; od = d; oi = i; }
      ++p;
    }
  }
  if (kind < 0) return;

  auto u1mat = [&](int d, int i) -> m2c {
    const float* pw = w + (d * 10 + i) * 5;
    m2c U = mmul(mrx(pw[2]), mmul(mrz(pw[1]), mrx(pw[0])));
    if (i == 0 && d > 0) {
      m2c U0 = mmul(mrz(w2[d - 1]), mrx(w1[d - 1]));
      U = mmul(U, U0);
    }
    return U;
  };
  auto cumat = [&](int d, int i) -> m2c {
    const float* pw = w + (d * 10 + i) * 5;
    return mmul(mrx(pw[4]), mrz(pw[3]));
  };

  m2c M0{}, M1{};
  int bt = 9;
  if (kind == 0) {
    M0 = madj(mmul(mrz(w2[4]), mrx(w1[4]))); M1 = M0; bt = 9;
  } else if (kind == 1) {
    M1 = madj(cumat(od, oi));
    M0 = m2c{ {1.f, 0.f}, {0.f, 0.f}, {0.f, 0.f}, {1.f, 0.f} };
    bt = 9 - oi;
  } else if (kind == 2) {
    m2c V1 = madj(u1mat(od + 1, oi));
    m2c VC = madj(cumat(od, oi));
    M0 = V1; M1 = mmul(VC, V1);
    bt = 9 - oi;
  } else {
    M0 = madj(u1mat(od, oi)); M1 = M0; bt = 9 - oi;
  }

  float* o = prog + t * 64;
  if (bt >= 8 || bt < 6) {
    #pragma unroll
    for (int v = 0; v < 4; ++v) {
      const bool hi = (v & 1) != 0;
      const m2c& M = (v >> 1) ? M1 : M0;
      const c2 cA = hi ? M.a11 : M.a00;
      const c2 cB = hi ? M.a10 : M.a01;
      o[v*8+0] = cA.r; o[v*8+1] = cA.r; o[v*8+2] = -cA.i; o[v*8+3] = cA.i;
      o[v*8+4] = cB.r; o[v*8+5] = cB.r; o[v*8+6] = -cB.i; o[v*8+7] = cB.i;
    }
  } else {
    const m2c* Ms[2] = {&M0, &M1};
    #pragma unroll
    for (int c = 0; c < 2; ++c) {
      const c2 e[4] = {Ms[c]->a00, Ms[c]->a01, Ms[c]->a10, Ms[c]->a11};
      #pragma unroll
      for (int q = 0; q < 4; ++q) {
        o[c*16 + q*4 + 0] = e[q].r; o[c*16 + q*4 + 1] = e[q].r;
        o[c*16 + q*4 + 2] = -e[q].i; o[c*16 + q*4 + 3] = e[q].i;
      }
    }
  }
}

struct CoefP { f32x2 Ar, Ai, Br, Bi; };
__device__ __forceinline__ CoefP ldcoef(const float* __restrict__ g, int v) {
  const float4* p = reinterpret_cast<const float4*>(g + v * 8);
  const float4 a = p[0], b = p[1];
  return { f32x2{a.x, a.y}, f32x2{a.z, a.w}, f32x2{b.x, b.y}, f32x2{b.z, b.w} };
}
struct MatP { f32x2 u00r, u00i, u01r, u01i, u10r, u10i, u11r, u11i; };
__device__ __forceinline__ MatP ldmat16(const float* __restrict__ g, int c) {
  const float4* p = reinterpret_cast<const float4*>(g + c * 16);
  const float4 a = p[0], b = p[1], cc = p[2], d = p[3];
  MatP m;
  m.u00r = f32x2{a.x, a.y};  m.u00i = f32x2{a.z, a.w};
  m.u01r = f32x2{b.x, b.y};  m.u01i = f32x2{b.z, b.w};
  m.u10r = f32x2{cc.x, cc.y}; m.u10i = f32x2{cc.z, cc.w};
  m.u11r = f32x2{d.x, d.y};  m.u11i = f32x2{d.z, d.w};
  return m;
}
__device__ __forceinline__ f32x2 capply(const CoefP& c, f32x2 own, f32x2 par) {
  return cmad(cmulp(c.Ar, c.Ai, own), c.Br, c.Bi, par);
}
__device__ __forceinline__ void mat_pair(const MatP& m, f32x2& a, f32x2& b) {
  const f32x2 na = cmad(cmulp(m.u00r, m.u00i, a), m.u01r, m.u01i, b);
  const f32x2 nb = cmad(cmulp(m.u10r, m.u10i, a), m.u11r, m.u11i, b);
  a = na; b = nb;
}

// One program op applied to TWO states (sA, sB share all coefficients).
// bt/bc compile-time after full unroll. lxb: 2048-entry f32x2 buffer.
__device__ __forceinline__ void apply_op(f32x2 (&sA)[4], f32x2 (&sB)[4],
                                         f32x2* lxb, const int wv,
                                         const int lane, const float* __restrict__ g,
                                         const int bt, const int bc) {
  if (bt >= 8) {
    const int tb = bt - 8;
    const int hi = (wv >> tb) & 1;
    #pragma unroll
    for (int k = 0; k < 4; ++k) {
      lxb[(wv * 4 + k) * 64 + lane] = sA[k];
      lxb[1024 + (wv * 4 + k) * 64 + lane] = sB[k];
    }
    __syncthreads();
    const int pw = wv ^ (1 << tb);
    f32x2 pA[4], pB[4];
    #pragma unroll
    for (int k = 0; k < 4; ++k) {
      pA[k] = lxb[(pw * 4 + k) * 64 + lane];
      pB[k] = lxb[1024 + (pw * 4 + k) * 64 + lane];
    }
    if (bc >= 8) {
      const int c = (wv >> (bc - 8)) & 1;
      const CoefP cf = ldcoef(g, hi + 2 * c);
      #pragma unroll
      for (int k = 0; k < 4; ++k) {
        sA[k] = capply(cf, sA[k], pA[k]);
        sB[k] = capply(cf, sB[k], pB[k]);
      }
    } else if (bc >= 6) {
      const int cb = bc - 6;
      const CoefP c0 = ldcoef(g, hi), c1 = ldcoef(g, hi + 2);
      #pragma unroll
      for (int k = 0; k < 4; ++k) {
        const CoefP& cf = ((k >> cb) & 1) ? c1 : c0;
        sA[k] = capply(cf, sA[k], pA[k]);
        sB[k] = capply(cf, sB[k], pB[k]);
      }
    } else if (bc >= 0) {
      const int c = (lane >> bc) & 1;
      const CoefP cf = ldcoef(g, hi + 2 * c);
      #pragma unroll
      for (int k = 0; k < 4; ++k) {
        sA[k] = capply(cf, sA[k], pA[k]);
        sB[k] = capply(cf, sB[k], pB[k]);
      }
    } else {
      const CoefP cf = ldcoef(g, hi);
      #pragma unroll
      for (int k = 0; k < 4; ++k) {
        sA[k] = capply(cf, sA[k], pA[k]);
        sB[k] = capply(cf, sB[k], pB[k]);
      }
    }
  } else if (bt >= 6) {
    const int tm = 1 << (bt - 6);
    if (bc >= 6 && bc < 8) {
      const int cb = bc - 6;
      const MatP m0 = ldmat16(g, 0), m1 = ldmat16(g, 1);
      #pragma unroll
      for (int k0 = 0; k0 < 4; ++k0) {
        if (k0 & tm) continue;
        const int k1 = k0 | tm;
        const MatP& m = ((k0 >> cb) & 1) ? m1 : m0;
        mat_pair(m, sA[k0], sA[k1]);
        mat_pair(m, sB[k0], sB[k1]);
      }
    } else {
      int c = 0;
      if (bc >= 8)      c = (wv >> (bc - 8)) & 1;
      else if (bc >= 0) c = (lane >> bc) & 1;
      const MatP m = ldmat16(g, c);
      #pragma unroll
      for (int k0 = 0; k0 < 4; ++k0) {
        if (k0 & tm) continue;
        const int k1 = k0 | tm;
        mat_pair(m, sA[k0], sA[k1]);
        mat_pair(m, sB[k0], sB[k1]);
      }
    }
  } else {
    const int lm = 1 << bt;
    const int hi = (lane >> bt) & 1;
    if (bc >= 6 && bc < 8) {
      const int cb = bc - 6;
      const CoefP c0 = ldcoef(g, hi), c1 = ldcoef(g, hi + 2);
      #pragma unroll
      for (int k = 0; k < 4; ++k) {
        const CoefP& cf = ((k >> cb) & 1) ? c1 : c0;
        const f32x2 pA = shfl_fast(sA[k], lm);
        const f32x2 pB = shfl_fast(sB[k], lm);
        sA[k] = capply(cf, sA[k], pA);
        sB[k] = capply(cf, sB[k], pB);
      }
    } else {
      int c = 1;
      if (bc >= 8)      c = (wv >> (bc - 8)) & 1;
      else if (bc >= 0) c = (lane >> bc) & 1;
      const CoefP cf = ldcoef(g, (bc >= 0) ? (hi + 2 * c) : hi);
      #pragma unroll
      for (int k = 0; k < 4; ++k) {
        const f32x2 pA = shfl_fast(sA[k], lm);
        const f32x2 pB = shfl_fast(sB[k], lm);
        sA[k] = capply(cf, sA[k], pA);
        sB[k] = capply(cf, sB[k], pB);
      }
    }
  }
}

// Fused prep. Blocks <512: build rows 2b, 2b+1 of U (4 waves, 2x4 f32x2/lane).
// Blocks >=512: xconv (832 cols, packed cvt).
__global__ __launch_bounds__(256) void qprep(const float* __restrict__ prog,
                                             const float* __restrict__ x,
                                             _Float16* __restrict__ Wt,
                                             _Float16* __restrict__ Xh) {
  const int tid = threadIdx.x;
  if (blockIdx.x >= 512) {
    const int t = (blockIdx.x - 512) * 256 + tid;
    const int b = t >> 7;
    const int j = (t & 127) * 8;
    if (j >= 832) return;
    union { fp16x2 h2[4]; f16x8 h8; } u;
    if (j < 784) {
      const float4* p = reinterpret_cast<const float4*>(x + (size_t)b * 784 + j);
      const float4 v0 = p[0], v1 = p[1];
      u.h2[0] = __builtin_amdgcn_cvt_pkrtz(v0.x, v0.y);
      u.h2[1] = __builtin_amdgcn_cvt_pkrtz(v0.z, v0.w);
      u.h2[2] = __builtin_amdgcn_cvt_pkrtz(v1.x, v1.y);
      u.h2[3] = __builtin_amdgcn_cvt_pkrtz(v1.z, v1.w);
    } else {
      #pragma unroll
      for (int q = 0; q < 4; ++q) u.h2[q] = __builtin_amdgcn_cvt_pkrtz(0.f, 0.f);
    }
    *reinterpret_cast<f16x8*>(Xh + (size_t)b * 1024 + j) = u.h8;
    return;
  }

  // ---- build_W: 2 states per block ----
  __shared__ f32x2 lx[2][2048];   // double-buffered exchange (2 x 16 KB)

  const int lane = tid & 63;
  const int wv = tid >> 6;
  const int n0 = blockIdx.x * 2;
  const int n1 = n0 + 1;

  f32x2 sA[4], sB[4];
  #pragma unroll
  for (int k = 0; k < 4; ++k) {
    const int j = (wv << 8) | (k << 6) | lane;
    sA[k].x = (j == n0) ? 1.f : 0.f; sA[k].y = 0.f;
    sB[k].x = (j == n1) ? 1.f : 0.f; sB[k].y = 0.f;
  }

  int p = 0, ph = 0;
  #pragma unroll
  for (int dd = 0; dd < 5; ++dd) {
    const int d = 4 - dd;
    if (d == 4) {
      apply_op(sA, sB, &lx[ph & 1][0], wv, lane, prog + p * 64, 9, -1);
      ++p; ++ph;
    }
    const int r = (d & 1) ? 3 : 1;
    #pragma unroll
    for (int ii = 0; ii < 10; ++ii) {
      const int i = 9 - ii;
      const int c = (i + r) % 10;
      const int bt = 9 - i, bc = 9 - c;
      apply_op(sA, sB, &lx[ph & 1][0], wv, lane, prog + p * 64, bt, bc);
      ++p; if (bt >= 8) ++ph;
    }
    #pragma unroll
    for (int ii = 0; ii < 10; ++ii) {
      const int i = 9 - ii;
      if (d >= 1 && fusable(d - 1, i)) continue;   // absorbed forward
      const int bt = 9 - i;
      apply_op(sA, sB, &lx[ph & 1][0], wv, lane, prog + p * 64, bt, -1);
      ++p; if (bt >= 8) ++ph;
    }
  }

  // psi = U^dagger e_n => U[n][j] = (s.x, -s.y)
  #pragma unroll
  for (int k = 0; k < 4; ++k) {
    const int j = (wv << 8) | (k << 6) | lane;
    Wt[(size_t)(2 * n0) * 1024 + j] = (_Float16)sA[k].x;
    Wt[(size_t)(2 * n0 + 1) * 1024 + j] = (_Float16)(-sA[k].y);
    Wt[(size_t)(2 * n1) * 1024 + j] = (_Float16)sB[k].x;
    Wt[(size_t)(2 * n1 + 1) * 1024 + j] = (_Float16)(-sB[k].y);
  }
}

// ---------------- LDS-staged GEMM (unchanged from R11) ----------------
#define GZ_NSTEP 13

__device__ __forceinline__ void stage_tiles(const _Float16* __restrict__ gA,
                                            const _Float16* __restrict__ gB,
                                            _Float16* sA, _Float16* sB,
                                            int k0, int wv, int lane) {
  const int rIn = lane >> 3;
  const int colh = ((lane & 7) ^ rIn) * 8;
  #pragma unroll
  for (int c = 0; c < 2; ++c) {
    const int chunk = wv * 2 + c;
    const size_t grow = (size_t)(chunk * 8 + rIn) * 1024 + k0 + colh;
    auto* la = (__attribute__((address_space(3))) void*)(sA + chunk * 512 + lane * 8);
    __builtin_amdgcn_global_load_lds(
        (const __attribute__((address_space(1))) void*)(gA + grow), la, 16, 0, 0);
    auto* lb = (__attribute__((address_space(3))) void*)(sB + chunk * 512 + lane * 8);
    __builtin_amdgcn_global_load_lds(
        (const __attribute__((address_space(1))) void*)(gB + grow), lb, 16, 0, 0);
  }
}

__device__ __forceinline__ int lds_off(int row, int slot) {
  return row * 64 + ((slot ^ (row & 7)) * 8);
}

__global__ __launch_bounds__(512) void gemm_z(const _Float16* __restrict__ Xh,
                                              const _Float16* __restrict__ Wt,
                                              float* __restrict__ part, int B) {
  __shared__ _Float16 smA[2][128 * 64];
  __shared__ _Float16 smB[2][128 * 64];

  const int tid = threadIdx.x;
  const int lane = tid & 63;
  const int wv = tid >> 6;
  const int wm = wv >> 1;
  const int wn = wv & 1;
  const int row0 = blockIdx.x * 128;
  const int n0 = blockIdx.y * 128;

  const _Float16* gA = Xh + (size_t)row0 * 1024;
  const _Float16* gB = Wt + (size_t)n0 * 1024;

  const int lr = lane & 15;
  const int lq = lane >> 4;

  f32x4v acc[2][4];
  #pragma unroll
  for (int m = 0; m < 2; ++m)
    #pragma unroll
    for (int f = 0; f < 4; ++f) acc[m][f] = f32x4v{0.f, 0.f, 0.f, 0.f};

  stage_tiles(gA, gB, smA[0], smB[0], 0, wv, lane);
  __syncthreads();

  for (int t = 0; t < GZ_NSTEP; ++t) {
    const int cur = t & 1;
    if (t + 1 < GZ_NSTEP)
      stage_tiles(gA, gB, smA[cur ^ 1], smB[cur ^ 1], (t + 1) * 64, wv, lane);

    #pragma unroll
    for (int kk = 0; kk < 2; ++kk) {
      const int slot = kk * 4 + lq;
      f16x8 a[2], b[4];
      #pragma unroll
      for (int m = 0; m < 2; ++m) {
        const int row = wm * 32 + m * 16 + lr;
        a[m] = *reinterpret_cast<const f16x8*>(&smA[cur][lds_off(row, slot)]);
      }
      #pragma unroll
      for (int f = 0; f < 4; ++f) {
        const int row = wn * 64 + f * 16 + lr;
        b[f] = *reinterpret_cast<const f16x8*>(&smB[cur][lds_off(row, slot)]);
      }
      #pragma unroll
      for (int m = 0; m < 2; ++m)
        #pragma unroll
        for (int f = 0; f < 4; ++f)
          acc[m][f] = __builtin_amdgcn_mfma_f32_16x16x32_f16(a[m], b[f], acc[m][f], 0, 0, 0);
    }
    __syncthreads();
  }

  const int pp = blockIdx.y * 2 + wn;
  #pragma unroll
  for (int m = 0; m < 2; ++m) {
    f32x4v p = f32x4v{0.f, 0.f, 0.f, 0.f};
    #pragma unroll
    for (int f = 0; f < 4; ++f) p += acc[m][f] * acc[m][f];
    #pragma unroll
    for (int msk = 1; msk < 16; msk <<= 1) {
      p.x += __shfl_xor(p.x, msk, 64);
      p.y += __shfl_xor(p.y, msk, 64);
      p.z += __shfl_xor(p.z, msk, 64);
      p.w += __shfl_xor(p.w, msk, 64);
    }
    if (lr == 0) {
      const int rbase = row0 + wm * 32 + m * 16 + lq * 4;
      float* dst = part + (size_t)pp * B + rbase;
      dst[0] = p.x; dst[1] = p.y; dst[2] = p.z; dst[3] = p.w;
    }
  }
}

// ---- NLL ----
__global__ __launch_bounds__(256) void nll_part(const float* __restrict__ part,
                                                const int* __restrict__ y,
                                                float* __restrict__ out2, int B) {
  const int row = blockIdx.x * 256 + threadIdx.x;
  float q0 = 0.f, q1 = 0.f, nn = 0.f;
  #pragma unroll
  for (int pp = 0; pp < 32; ++pp) {
    const float P = part[(size_t)pp * B + row];
    q0 += (pp & 16) ? -P : P;
    q1 += (pp & 8) ? -P : P;
    nn += P;
  }
  const float z0 = q0 / nn, z1 = q1 / nn;
  const float mx = fmaxf(z0, z1);
  const float lse = mx + logf(expf(z0 - mx) + expf(z1 - mx));
  const float ly = (y[row] == 0) ? z0 : z1;
  float s = lse - ly;
  #pragma unroll
  for (int msk = 1; msk < 64; msk <<= 1) s += __shfl_xor(s, msk, 64);
  __shared__ float red[4];
  if ((threadIdx.x & 63) == 0) red[threadIdx.x >> 6] = s;
  __syncthreads();
  if (threadIdx.x == 0) out2[blockIdx.x] = red[0] + red[1] + red[2] + red[3];
}

__global__ void nll_final(const float* __restrict__ out2, float* __restrict__ out,
                          int nblk, float scale) {
  const int t = threadIdx.x;
  float s = (t < nblk) ? out2[t] : 0.f;
  #pragma unroll
  for (int msk = 1; msk < 64; msk <<= 1) s += __shfl_xor(s, msk, 64);
  if (t == 0) out[0] = s * scale;
}

} // namespace

extern "C" void kernel_launch(void* const* d_in, const int* in_sizes, int n_in,
                              void* d_out, int out_size, void* d_ws, size_t ws_size,
                              hipStream_t stream) {
  const float* x  = (const float*)d_in[0];
  const int*   y  = (const int*)d_in[1];
  const float* w  = (const float*)d_in[2];
  const float* w1 = (const float*)d_in[3];
  const float* w2 = (const float*)d_in[4];
  float* out = (float*)d_out;

  const int B = in_sizes[0] / 784;      // 8192

  char* ws = (char*)d_ws;
  _Float16* Wt   = (_Float16*)ws;                                // 4 MB
  _Float16* Xh   = (_Float16*)(ws + (size_t)2048 * 1024 * 2);    // 16 MB
  float*    part = (float*)(ws + (size_t)2048 * 1024 * 2 + (size_t)B * 1024 * 2);
  float*    out2 = part + (size_t)32 * B;
  float*    prog = out2 + 64;           // 69*64 floats

  make_prog<<<1, 128, 0, stream>>>(w, w1, w2, prog);
  qprep<<<512 + (B * 128) / 256, 256, 0, stream>>>(prog, x, Wt, Xh);
  gemm_z<<<dim3(B / 128, 16), 512, 0, stream>>>(Xh, Wt, part, B);
  nll_part<<<B / 256, 256, 0, stream>>>(part, y, out2, B);
  nll_final<<<1, 64, 0, stream>>>(out2, out, B / 256, 1.0f / (float)B);
}

// Round 18
// 75.369 us; speedup vs baseline: 1.1815x; 1.0384x over previous
//
#include <hip/hip_runtime.h>

// CCQC classifier, GEMM formulation. R18: j-bit role remap + fewer dispatches.
//   j = (k<<8)|(wv<<6)|lane  (was (wv<<8)|(k<<6)|lane).
//   Per-wire target-op counts after fusion: wire0=11, wires1,2=8, wires3-9=6.
//   k-bits (j 9,8) = wires 0,1 -> 19 ops as in-register pairs (no barrier).
//   wave bits (j 7,6) = wires 2,3 -> 14 LDS exchanges (was 19 barriers).
//   lane bits (j 5..0) = wires 4..9 -> 36 shuffles (DPP for j-bits 0,1).
//   nll_final dropped: make_prog zeroes out[0]; nll_part atomicAdds partials.
//   Rest: R16/17 fused 69-op variant-table program, 2 states per build block,
//   gemm_z 128x128 BK=64 8-wave + XOR swizzle, fused |psi|^2 epilogue.

namespace {

typedef float f32x2 __attribute__((ext_vector_type(2)));
typedef __fp16 fp16x2 __attribute__((ext_vector_type(2)));
typedef _Float16 f16x8 __attribute__((ext_vector_type(8)));
typedef float f32x4v __attribute__((ext_vector_type(4)));

// ---- packed dual-f32 ops (VOP3P), untied operands ----
__device__ __forceinline__ f32x2 pk_mul(f32x2 a, f32x2 b) {
  f32x2 d;
  asm("v_pk_mul_f32 %0, %1, %2" : "=v"(d) : "v"(a), "v"(b));
  return d;
}
__device__ __forceinline__ f32x2 pk_fma(f32x2 a, f32x2 b, f32x2 c) {
  f32x2 d;
  asm("v_pk_fma_f32 %0, %1, %2, %3" : "=v"(d) : "v"(a), "v"(b), "v"(c));
  return d;
}
__device__ __forceinline__ f32x2 pk_fma_swap1(f32x2 a, f32x2 b, f32x2 c) {
  f32x2 d;
  asm("v_pk_fma_f32 %0, %1, %2, %3 op_sel:[0,1,0] op_sel_hi:[1,0,1]"
      : "=v"(d) : "v"(a), "v"(b), "v"(c));
  return d;
}
__device__ __forceinline__ f32x2 cmulp(f32x2 cr2, f32x2 ci2, f32x2 v) {
  return pk_fma_swap1(ci2, v, pk_mul(cr2, v));
}
__device__ __forceinline__ f32x2 cmad(f32x2 acc, f32x2 cr2, f32x2 ci2, f32x2 v) {
  return pk_fma_swap1(ci2, v, pk_fma(cr2, v, acc));
}

__device__ __forceinline__ f32x2 shfl_xor2(f32x2 v, int lm) {
  f32x2 r;
  r.x = __shfl_xor(v.x, lm, 64);
  r.y = __shfl_xor(v.y, lm, 64);
  return r;
}
template <int CTRL>
__device__ __forceinline__ f32x2 dpp_xor2(f32x2 v) {
  f32x2 r;
  const int ix = __builtin_bit_cast(int, v.x);
  const int iy = __builtin_bit_cast(int, v.y);
  r.x = __builtin_bit_cast(float,
      __builtin_amdgcn_update_dpp(0, ix, CTRL, 0xF, 0xF, true));
  r.y = __builtin_bit_cast(float,
      __builtin_amdgcn_update_dpp(0, iy, CTRL, 0xF, 0xF, true));
  return r;
}
__device__ __forceinline__ f32x2 shfl_fast(f32x2 v, const int lm) {
  if (lm == 1) return dpp_xor2<0xB1>(v);
  if (lm == 2) return dpp_xor2<0x4E>(v);
  return shfl_xor2(v, lm);
}

struct c2 { float r, i; };
struct m2c { c2 a00, a01, a10, a11; };

__device__ __forceinline__ c2 cmul(c2 x, c2 y) { return {x.r*y.r - x.i*y.i, x.r*y.i + x.i*y.r}; }
__device__ __forceinline__ c2 cadd(c2 x, c2 y) { return {x.r + y.r, x.i + y.i}; }
__device__ __forceinline__ c2 conjc(c2 a) { return {a.r, -a.i}; }
__device__ __forceinline__ m2c mmul(m2c A, m2c B) {
  m2c C;
  C.a00 = cadd(cmul(A.a00, B.a00), cmul(A.a01, B.a10));
  C.a01 = cadd(cmul(A.a00, B.a01), cmul(A.a01, B.a11));
  C.a10 = cadd(cmul(A.a10, B.a00), cmul(A.a11, B.a10));
  C.a11 = cadd(cmul(A.a10, B.a01), cmul(A.a11, B.a11));
  return C;
}
__device__ __forceinline__ m2c madj(m2c U) {
  return { conjc(U.a00), conjc(U.a10), conjc(U.a01), conjc(U.a11) };
}
__device__ __forceinline__ m2c mrx(float t) {
  float c = cosf(0.5f * t), s = sinf(0.5f * t);
  return { {c, 0.f}, {0.f, -s}, {0.f, -s}, {c, 0.f} };
}
__device__ __forceinline__ m2c mrz(float t) {
  float c = cosf(0.5f * t), s = sinf(0.5f * t);
  return { {c, -s}, {0.f, 0.f}, {0.f, 0.f}, {c, s} };
}

// fusable(d,i): CU[i](d) absorbs U1[i](d+1). r(d)=1 (d even): i>=1; r=3: i>=3.
__device__ __forceinline__ bool fusable(int d, int i) {
  return (d & 1) ? (i >= 3) : (i >= 1);
}

// 69-op program, 64 floats/op.
//  k-target ops (bt>=8): matrix form, M0 packed16 at o[0], M1 at o[16].
//  other ops: coef form, 4 variants v = hi + 2*c at o[v*8]:
//    {cA.r,cA.r,-cA.i,cA.i, cB.r,cB.r,-cB.i,cB.i}, M = c? M1:M0.
//  M0/M1: unfused no-ctrl: both adj; unfused ctrl: {I, adj(CU)};
//  fused: {adj(U1), adj(CU)*adj(U1)}.
// Thread 127 zeroes out[0] (replays don't re-poison; nll atomicAdds into it).
__global__ void make_prog(const float* __restrict__ w, const float* __restrict__ w1,
                          const float* __restrict__ w2, float* __restrict__ prog,
                          float* __restrict__ outp) {
  const int t = threadIdx.x;
  if (t == 127) outp[0] = 0.f;
  int kind = -1, od = 0, oi = 0, p = 0;
  for (int dd = 0; dd < 5; ++dd) {
    const int d = 4 - dd;
    if (d == 4) { if (p == t) kind = 0; ++p; }
    for (int ii = 0; ii < 10; ++ii) {
      const int i = 9 - ii;
      if (p == t) { kind = (d <= 3 && fusable(d, i)) ? 2 : 1; od = d; oi = i; }
      ++p;
    }
    for (int ii = 0; ii < 10; ++ii) {
      const int i = 9 - ii;
      if (d >= 1 && fusable(d - 1, i)) continue;
      if (p == t) { kind = 3; od = d; oi = i; }
      ++p;
    }
  }
  if (kind < 0) return;

  auto u1mat = [&](int d, int i) -> m2c {
    const float* pw = w + (d * 10 + i) * 5;
    m2c U = mmul(mrx(pw[2]), mmul(mrz(pw[1]), mrx(pw[0])));
    if (i == 0 && d > 0) {
      m2c U0 = mmul(mrz(w2[d - 1]), mrx(w1[d - 1]));
      U = mmul(U, U0);
    }
    return U;
  };
  auto cumat = [&](int d, int i) -> m2c {
    const float* pw = w + (d * 10 + i) * 5;
    return mmul(mrx(pw[4]), mrz(pw[3]));
  };

  m2c M0{}, M1{};
  int bt = 9;
  if (kind == 0) {
    M0 = madj(mmul(mrz(w2[4]), mrx(w1[4]))); M1 = M0; bt = 9;
  } else if (kind == 1) {
    M1 = madj(cumat(od, oi));
    M0 = m2c{ {1.f, 0.f}, {0.f, 0.f}, {0.f, 0.f}, {1.f, 0.f} };
    bt = 9 - oi;
  } else if (kind == 2) {
    m2c V1 = madj(u1mat(od + 1, oi));
    m2c VC = madj(cumat(od, oi));
    M0 = V1; M1 = mmul(VC, V1);
    bt = 9 - oi;
  } else {
    M0 = madj(u1mat(od, oi)); M1 = M0; bt = 9 - oi;
  }

  float* o = prog + t * 64;
  if (bt >= 8) {
    // matrix form (k-register target)
    const m2c* Ms[2] = {&M0, &M1};
    #pragma unroll
    for (int c = 0; c < 2; ++c) {
      const c2 e[4] = {Ms[c]->a00, Ms[c]->a01, Ms[c]->a10, Ms[c]->a11};
      #pragma unroll
      for (int q = 0; q < 4; ++q) {
        o[c*16 + q*4 + 0] = e[q].r; o[c*16 + q*4 + 1] = e[q].r;
        o[c*16 + q*4 + 2] = -e[q].i; o[c*16 + q*4 + 3] = e[q].i;
      }
    }
  } else {
    // coef form (exchange or shuffle target)
    #pragma unroll
    for (int v = 0; v < 4; ++v) {
      const bool hi = (v & 1) != 0;
      const m2c& M = (v >> 1) ? M1 : M0;
      const c2 cA = hi ? M.a11 : M.a00;
      const c2 cB = hi ? M.a10 : M.a01;
      o[v*8+0] = cA.r; o[v*8+1] = cA.r; o[v*8+2] = -cA.i; o[v*8+3] = cA.i;
      o[v*8+4] = cB.r; o[v*8+5] = cB.r; o[v*8+6] = -cB.i; o[v*8+7] = cB.i;
    }
  }
}

struct CoefP { f32x2 Ar, Ai, Br, Bi; };
__device__ __forceinline__ CoefP ldcoef(const float* __restrict__ g, int v) {
  const float4* p = reinterpret_cast<const float4*>(g + v * 8);
  const float4 a = p[0], b = p[1];
  return { f32x2{a.x, a.y}, f32x2{a.z, a.w}, f32x2{b.x, b.y}, f32x2{b.z, b.w} };
}
struct MatP { f32x2 u00r, u00i, u01r, u01i, u10r, u10i, u11r, u11i; };
__device__ __forceinline__ MatP ldmat16(const float* __restrict__ g, int c) {
  const float4* p = reinterpret_cast<const float4*>(g + c * 16);
  const float4 a = p[0], b = p[1], cc = p[2], d = p[3];
  MatP m;
  m.u00r = f32x2{a.x, a.y};  m.u00i = f32x2{a.z, a.w};
  m.u01r = f32x2{b.x, b.y};  m.u01i = f32x2{b.z, b.w};
  m.u10r = f32x2{cc.x, cc.y}; m.u10i = f32x2{cc.z, cc.w};
  m.u11r = f32x2{d.x, d.y};  m.u11i = f32x2{d.z, d.w};
  return m;
}
__device__ __forceinline__ f32x2 capply(const CoefP& c, f32x2 own, f32x2 par) {
  return cmad(cmulp(c.Ar, c.Ai, own), c.Br, c.Bi, par);
}
__device__ __forceinline__ void mat_pair(const MatP& m, f32x2& a, f32x2& b) {
  const f32x2 na = cmad(cmulp(m.u00r, m.u00i, a), m.u01r, m.u01i, b);
  const f32x2 nb = cmad(cmulp(m.u10r, m.u10i, a), m.u11r, m.u11i, b);
  a = na; b = nb;
}

// One program op on TWO states. j = (k<<8)|(wv<<6)|lane.
//   bt>=8: k-register pair (tm = 1<<(bt-8)), matrix form.
//   bt in {6,7}: cross-wave exchange (tb = bt-6), coef form, 1 barrier.
//   bt<6: lane shuffle (lm = 1<<bt), coef form.
// ctrl bc: >=8 per-k (cb=bc-8); {6,7} wave-uniform; [0,6) per-lane; <0 none.
__device__ __forceinline__ void apply_op(f32x2 (&sA)[4], f32x2 (&sB)[4],
                                         f32x2* lxb, const int wv,
                                         const int lane, const float* __restrict__ g,
                                         const int bt, const int bc) {
  if (bt >= 8) {
    const int tm = 1 << (bt - 8);
    if (bc >= 8) {
      const int cb = bc - 8;
      const MatP m0 = ldmat16(g, 0), m1 = ldmat16(g, 1);
      #pragma unroll
      for (int k0 = 0; k0 < 4; ++k0) {
        if (k0 & tm) continue;
        const int k1 = k0 | tm;
        const MatP& m = ((k0 >> cb) & 1) ? m1 : m0;
        mat_pair(m, sA[k0], sA[k1]);
        mat_pair(m, sB[k0], sB[k1]);
      }
    } else {
      int c = 0;
      if (bc >= 6)      c = (wv >> (bc - 6)) & 1;
      else if (bc >= 0) c = (lane >> bc) & 1;
      const MatP m = ldmat16(g, c);
      #pragma unroll
      for (int k0 = 0; k0 < 4; ++k0) {
        if (k0 & tm) continue;
        const int k1 = k0 | tm;
        mat_pair(m, sA[k0], sA[k1]);
        mat_pair(m, sB[k0], sB[k1]);
      }
    }
  } else if (bt >= 6) {
    const int tb = bt - 6;
    const int hi = (wv >> tb) & 1;
    #pragma unroll
    for (int k = 0; k < 4; ++k) {
      lxb[(wv * 4 + k) * 64 + lane] = sA[k];
      lxb[1024 + (wv * 4 + k) * 64 + lane] = sB[k];
    }
    __syncthreads();
    const int pw = wv ^ (1 << tb);
    f32x2 pA[4], pB[4];
    #pragma unroll
    for (int k = 0; k < 4; ++k) {
      pA[k] = lxb[(pw * 4 + k) * 64 + lane];
      pB[k] = lxb[1024 + (pw * 4 + k) * 64 + lane];
    }
    if (bc >= 8) {
      const int cb = bc - 8;
      const CoefP c0 = ldcoef(g, hi), c1 = ldcoef(g, hi + 2);
      #pragma unroll
      for (int k = 0; k < 4; ++k) {
        const CoefP& cf = ((k >> cb) & 1) ? c1 : c0;
        sA[k] = capply(cf, sA[k], pA[k]);
        sB[k] = capply(cf, sB[k], pB[k]);
      }
    } else {
      int c = 0;
      if (bc >= 6)      c = (wv >> (bc - 6)) & 1;
      else if (bc >= 0) c = (lane >> bc) & 1;
      const CoefP cf = ldcoef(g, hi + 2 * c);
      #pragma unroll
      for (int k = 0; k < 4; ++k) {
        sA[k] = capply(cf, sA[k], pA[k]);
        sB[k] = capply(cf, sB[k], pB[k]);
      }
    }
  } else {
    const int lm = 1 << bt;
    const int hi = (lane >> bt) & 1;
    if (bc >= 8) {
      const int cb = bc - 8;
      const CoefP c0 = ldcoef(g, hi), c1 = ldcoef(g, hi + 2);
      #pragma unroll
      for (int k = 0; k < 4; ++k) {
        const CoefP& cf = ((k >> cb) & 1) ? c1 : c0;
        const f32x2 pA = shfl_fast(sA[k], lm);
        const f32x2 pB = shfl_fast(sB[k], lm);
        sA[k] = capply(cf, sA[k], pA);
        sB[k] = capply(cf, sB[k], pB);
      }
    } else {
      int c = 0;
      if (bc >= 6)      c = (wv >> (bc - 6)) & 1;
      else if (bc >= 0) c = (lane >> bc) & 1;
      const CoefP cf = ldcoef(g, hi + 2 * c);
      #pragma unroll
      for (int k = 0; k < 4; ++k) {
        const f32x2 pA = shfl_fast(sA[k], lm);
        const f32x2 pB = shfl_fast(sB[k], lm);
        sA[k] = capply(cf, sA[k], pA);
        sB[k] = capply(cf, sB[k], pB);
      }
    }
  }
}

// Fused prep. Blocks <512: build rows 2b, 2b+1 of U (4 waves, 2x4 f32x2/lane).
// Blocks >=512: xconv (832 cols, packed cvt).
__global__ __launch_bounds__(256) void qprep(const float* __restrict__ prog,
                                             const float* __restrict__ x,
                                             _Float16* __restrict__ Wt,
                                             _Float16* __restrict__ Xh) {
  const int tid = threadIdx.x;
  if (blockIdx.x >= 512) {
    const int t = (blockIdx.x - 512) * 256 + tid;
    const int b = t >> 7;
    const int j = (t & 127) * 8;
    if (j >= 832) return;
    union { fp16x2 h2[4]; f16x8 h8; } u;
    if (j < 784) {
      const float4* p = reinterpret_cast<const float4*>(x + (size_t)b * 784 + j);
      const float4 v0 = p[0], v1 = p[1];
      u.h2[0] = __builtin_amdgcn_cvt_pkrtz(v0.x, v0.y);
      u.h2[1] = __builtin_amdgcn_cvt_pkrtz(v0.z, v0.w);
      u.h2[2] = __builtin_amdgcn_cvt_pkrtz(v1.x, v1.y);
      u.h2[3] = __builtin_amdgcn_cvt_pkrtz(v1.z, v1.w);
    } else {
      #pragma unroll
      for (int q = 0; q < 4; ++q) u.h2[q] = __builtin_amdgcn_cvt_pkrtz(0.f, 0.f);
    }
    *reinterpret_cast<f16x8*>(Xh + (size_t)b * 1024 + j) = u.h8;
    return;
  }

  // ---- build_W: 2 states per block ----
  __shared__ f32x2 lx[2][2048];   // double-buffered exchange (2 x 16 KB)

  const int lane = tid & 63;
  const int wv = tid >> 6;
  const int n0 = blockIdx.x * 2;
  const int n1 = n0 + 1;

  f32x2 sA[4], sB[4];
  #pragma unroll
  for (int k = 0; k < 4; ++k) {
    const int j = (k << 8) | (wv << 6) | lane;
    sA[k].x = (j == n0) ? 1.f : 0.f; sA[k].y = 0.f;
    sB[k].x = (j == n1) ? 1.f : 0.f; sB[k].y = 0.f;
  }

  int p = 0, ph = 0;
  #pragma unroll
  for (int dd = 0; dd < 5; ++dd) {
    const int d = 4 - dd;
    if (d == 4) {
      apply_op(sA, sB, &lx[ph & 1][0], wv, lane, prog + p * 64, 9, -1);
      ++p;   // bt=9: k-reg op, no barrier
    }
    const int r = (d & 1) ? 3 : 1;
    #pragma unroll
    for (int ii = 0; ii < 10; ++ii) {
      const int i = 9 - ii;
      const int c = (i + r) % 10;
      const int bt = 9 - i, bc = 9 - c;
      apply_op(sA, sB, &lx[ph & 1][0], wv, lane, prog + p * 64, bt, bc);
      ++p; if (bt >= 6 && bt < 8) ++ph;
    }
    #pragma unroll
    for (int ii = 0; ii < 10; ++ii) {
      const int i = 9 - ii;
      if (d >= 1 && fusable(d - 1, i)) continue;   // absorbed forward
      const int bt = 9 - i;
      apply_op(sA, sB, &lx[ph & 1][0], wv, lane, prog + p * 64, bt, -1);
      ++p; if (bt >= 6 && bt < 8) ++ph;
    }
  }

  // psi = U^dagger e_n => U[n][j] = (s.x, -s.y); j = (k<<8)|(wv<<6)|lane
  #pragma unroll
  for (int k = 0; k < 4; ++k) {
    const int j = (k << 8) | (wv << 6) | lane;
    Wt[(size_t)(2 * n0) * 1024 + j] = (_Float16)sA[k].x;
    Wt[(size_t)(2 * n0 + 1) * 1024 + j] = (_Float16)(-sA[k].y);
    Wt[(size_t)(2 * n1) * 1024 + j] = (_Float16)sB[k].x;
    Wt[(size_t)(2 * n1 + 1) * 1024 + j] = (_Float16)(-sB[k].y);
  }
}

// ---------------- LDS-staged GEMM (unchanged from R11) ----------------
#define GZ_NSTEP 13

__device__ __forceinline__ void stage_tiles(const _Float16* __restrict__ gA,
                                            const _Float16* __restrict__ gB,
                                            _Float16* sA, _Float16* sB,
                                            int k0, int wv, int lane) {
  const int rIn = lane >> 3;
  const int colh = ((lane & 7) ^ rIn) * 8;
  #pragma unroll
  for (int c = 0; c < 2; ++c) {
    const int chunk = wv * 2 + c;
    const size_t grow = (size_t)(chunk * 8 + rIn) * 1024 + k0 + colh;
    auto* la = (__attribute__((address_space(3))) void*)(sA + chunk * 512 + lane * 8);
    __builtin_amdgcn_global_load_lds(
        (const __attribute__((address_space(1))) void*)(gA + grow), la, 16, 0, 0);
    auto* lb = (__attribute__((address_space(3))) void*)(sB + chunk * 512 + lane * 8);
    __builtin_amdgcn_global_load_lds(
        (const __attribute__((address_space(1))) void*)(gB + grow), lb, 16, 0, 0);
  }
}

__device__ __forceinline__ int lds_off(int row, int slot) {
  return row * 64 + ((slot ^ (row & 7)) * 8);
}

__global__ __launch_bounds__(512) void gemm_z(const _Float16* __restrict__ Xh,
                                              const _Float16* __restrict__ Wt,
                                              float* __restrict__ part, int B) {
  __shared__ _Float16 smA[2][128 * 64];
  __shared__ _Float16 smB[2][128 * 64];

  const int tid = threadIdx.x;
  const int lane = tid & 63;
  const int wv = tid >> 6;
  const int wm = wv >> 1;
  const int wn = wv & 1;
  const int row0 = blockIdx.x * 128;
  const int n0 = blockIdx.y * 128;

  const _Float16* gA = Xh + (size_t)row0 * 1024;
  const _Float16* gB = Wt + (size_t)n0 * 1024;

  const int lr = lane & 15;
  const int lq = lane >> 4;

  f32x4v acc[2][4];
  #pragma unroll
  for (int m = 0; m < 2; ++m)
    #pragma unroll
    for (int f = 0; f < 4; ++f) acc[m][f] = f32x4v{0.f, 0.f, 0.f, 0.f};

  stage_tiles(gA, gB, smA[0], smB[0], 0, wv, lane);
  __syncthreads();

  for (int t = 0; t < GZ_NSTEP; ++t) {
    const int cur = t & 1;
    if (t + 1 < GZ_NSTEP)
      stage_tiles(gA, gB, smA[cur ^ 1], smB[cur ^ 1], (t + 1) * 64, wv, lane);

    #pragma unroll
    for (int kk = 0; kk < 2; ++kk) {
      const int slot = kk * 4 + lq;
      f16x8 a[2], b[4];
      #pragma unroll
      for (int m = 0; m < 2; ++m) {
        const int row = wm * 32 + m * 16 + lr;
        a[m] = *reinterpret_cast<const f16x8*>(&smA[cur][lds_off(row, slot)]);
      }
      #pragma unroll
      for (int f = 0; f < 4; ++f) {
        const int row = wn * 64 + f * 16 + lr;
        b[f] = *reinterpret_cast<const f16x8*>(&smB[cur][lds_off(row, slot)]);
      }
      #pragma unroll
      for (int m = 0; m < 2; ++m)
        #pragma unroll
        for (int f = 0; f < 4; ++f)
          acc[m][f] = __builtin_amdgcn_mfma_f32_16x16x32_f16(a[m], b[f], acc[m][f], 0, 0, 0);
    }
    __syncthreads();
  }

  const int pp = blockIdx.y * 2 + wn;
  #pragma unroll
  for (int m = 0; m < 2; ++m) {
    f32x4v p = f32x4v{0.f, 0.f, 0.f, 0.f};
    #pragma unroll
    for (int f = 0; f < 4; ++f) p += acc[m][f] * acc[m][f];
    #pragma unroll
    for (int msk = 1; msk < 16; msk <<= 1) {
      p.x += __shfl_xor(p.x, msk, 64);
      p.y += __shfl_xor(p.y, msk, 64);
      p.z += __shfl_xor(p.z, msk, 64);
      p.w += __shfl_xor(p.w, msk, 64);
    }
    if (lr == 0) {
      const int rbase = row0 + wm * 32 + m * 16 + lq * 4;
      float* dst = part + (size_t)pp * B + rbase;
      dst[0] = p.x; dst[1] = p.y; dst[2] = p.z; dst[3] = p.w;
    }
  }
}

// ---- NLL: per-block partial, atomicAdd of scaled sum into out[0] ----
// (out[0] zeroed by make_prog each call; fp-atomic order jitter ~1e-6 << thr)
__global__ __launch_bounds__(256) void nll_part(const float* __restrict__ part,
                                                const int* __restrict__ y,
                                                float* __restrict__ out, int B,
                                                float scale) {
  const int row = blockIdx.x * 256 + threadIdx.x;
  float q0 = 0.f, q1 = 0.f, nn = 0.f;
  #pragma unroll
  for (int pp = 0; pp < 32; ++pp) {
    const float P = part[(size_t)pp * B + row];
    q0 += (pp & 16) ? -P : P;
    q1 += (pp & 8) ? -P : P;
    nn += P;
  }
  const float z0 = q0 / nn, z1 = q1 / nn;
  const float mx = fmaxf(z0, z1);
  const float lse = mx + logf(expf(z0 - mx) + expf(z1 - mx));
  const float ly = (y[row] == 0) ? z0 : z1;
  float s = lse - ly;
  #pragma unroll
  for (int msk = 1; msk < 64; msk <<= 1) s += __shfl_xor(s, msk, 64);
  __shared__ float red[4];
  if ((threadIdx.x & 63) == 0) red[threadIdx.x >> 6] = s;
  __syncthreads();
  if (threadIdx.x == 0)
    atomicAdd(out, (red[0] + red[1] + red[2] + red[3]) * scale);
}

} // namespace

extern "C" void kernel_launch(void* const* d_in, const int* in_sizes, int n_in,
                              void* d_out, int out_size, void* d_ws, size_t ws_size,
                              hipStream_t stream) {
  const float* x  = (const float*)d_in[0];
  const int*   y  = (const int*)d_in[1];
  const float* w  = (const float*)d_in[2];
  const float* w1 = (const float*)d_in[3];
  const float* w2 = (const float*)d_in[4];
  float* out = (float*)d_out;

  const int B = in_sizes[0] / 784;      // 8192

  char* ws = (char*)d_ws;
  _Float16* Wt   = (_Float16*)ws;                                // 4 MB
  _Float16* Xh   = (_Float16*)(ws + (size_t)2048 * 1024 * 2);    // 16 MB
  float*    part = (float*)(ws + (size_t)2048 * 1024 * 2 + (size_t)B * 1024 * 2);
  float*    prog = part + (size_t)32 * B;   // 69*64 floats

  make_prog<<<1, 128, 0, stream>>>(w, w1, w2, prog, out);
  qprep<<<512 + (B * 128) / 256, 256, 0, stream>>>(prog, x, Wt, Xh);
  gemm_z<<<dim3(B / 128, 16), 512, 0, stream>>>(Xh, Wt, part, B);
  nll_part<<<B / 256, 256, 0, stream>>>(part, y, out, B, 1.0f / (float)B);
}

// Round 19
// 73.856 us; speedup vs baseline: 1.2057x; 1.0205x over previous
//
#include <hip/hip_runtime.h>

// CCQC classifier, GEMM formulation. R19: 3 k-bits / 128-thread build blocks.
//   j = (k<<7)|(wv<<6)|lane, k in [0,8), 2 waves/block, 1 state/block.
//   Wires 0,1,2 (27 fused ops) -> in-register k-pairs (no barrier/shuffle).
//   Wire 3 (6 ops) -> single-wave-bit LDS exchange (6 barriers, 128 thr).
//   Wires 4-9 (36 ops) -> lane shuffles (DPP for j-bits 0,1).
//   1024 independent build blocks -> ~8 blocks/CU; barrier stalls overlap
//   across blocks (R17/R18: 4-wave blocks x 2/CU coupled all waves).
//   Program: fused 69-op reversed-adjoint variant tables (matrix form for
//   bt>=7, coef form otherwise). nll atomicAdd (out zeroed by make_prog).
//   gemm_z: 128x128 BK=64 8-wave + XOR swizzle, fused |psi|^2 epilogue.

namespace {

typedef float f32x2 __attribute__((ext_vector_type(2)));
typedef __fp16 fp16x2 __attribute__((ext_vector_type(2)));
typedef _Float16 f16x8 __attribute__((ext_vector_type(8)));
typedef float f32x4v __attribute__((ext_vector_type(4)));

// ---- packed dual-f32 ops (VOP3P), untied operands ----
__device__ __forceinline__ f32x2 pk_mul(f32x2 a, f32x2 b) {
  f32x2 d;
  asm("v_pk_mul_f32 %0, %1, %2" : "=v"(d) : "v"(a), "v"(b));
  return d;
}
__device__ __forceinline__ f32x2 pk_fma(f32x2 a, f32x2 b, f32x2 c) {
  f32x2 d;
  asm("v_pk_fma_f32 %0, %1, %2, %3" : "=v"(d) : "v"(a), "v"(b), "v"(c));
  return d;
}
__device__ __forceinline__ f32x2 pk_fma_swap1(f32x2 a, f32x2 b, f32x2 c) {
  f32x2 d;
  asm("v_pk_fma_f32 %0, %1, %2, %3 op_sel:[0,1,0] op_sel_hi:[1,0,1]"
      : "=v"(d) : "v"(a), "v"(b), "v"(c));
  return d;
}
__device__ __forceinline__ f32x2 cmulp(f32x2 cr2, f32x2 ci2, f32x2 v) {
  return pk_fma_swap1(ci2, v, pk_mul(cr2, v));
}
__device__ __forceinline__ f32x2 cmad(f32x2 acc, f32x2 cr2, f32x2 ci2, f32x2 v) {
  return pk_fma_swap1(ci2, v, pk_fma(cr2, v, acc));
}

__device__ __forceinline__ f32x2 shfl_xor2(f32x2 v, int lm) {
  f32x2 r;
  r.x = __shfl_xor(v.x, lm, 64);
  r.y = __shfl_xor(v.y, lm, 64);
  return r;
}
template <int CTRL>
__device__ __forceinline__ f32x2 dpp_xor2(f32x2 v) {
  f32x2 r;
  const int ix = __builtin_bit_cast(int, v.x);
  const int iy = __builtin_bit_cast(int, v.y);
  r.x = __builtin_bit_cast(float,
      __builtin_amdgcn_update_dpp(0, ix, CTRL, 0xF, 0xF, true));
  r.y = __builtin_bit_cast(float,
      __builtin_amdgcn_update_dpp(0, iy, CTRL, 0xF, 0xF, true));
  return r;
}
__device__ __forceinline__ f32x2 shfl_fast(f32x2 v, const int lm) {
  if (lm == 1) return dpp_xor2<0xB1>(v);
  if (lm == 2) return dpp_xor2<0x4E>(v);
  return shfl_xor2(v, lm);
}

struct c2 { float r, i; };
struct m2c { c2 a00, a01, a10, a11; };

__device__ __forceinline__ c2 cmul(c2 x, c2 y) { return {x.r*y.r - x.i*y.i, x.r*y.i + x.i*y.r}; }
__device__ __forceinline__ c2 cadd(c2 x, c2 y) { return {x.r + y.r, x.i + y.i}; }
__device__ __forceinline__ c2 conjc(c2 a) { return {a.r, -a.i}; }
__device__ __forceinline__ m2c mmul(m2c A, m2c B) {
  m2c C;
  C.a00 = cadd(cmul(A.a00, B.a00), cmul(A.a01, B.a10));
  C.a01 = cadd(cmul(A.a00, B.a01), cmul(A.a01, B.a11));
  C.a10 = cadd(cmul(A.a10, B.a00), cmul(A.a11, B.a10));
  C.a11 = cadd(cmul(A.a10, B.a01), cmul(A.a11, B.a11));
  return C;
}
__device__ __forceinline__ m2c madj(m2c U) {
  return { conjc(U.a00), conjc(U.a10), conjc(U.a01), conjc(U.a11) };
}
__device__ __forceinline__ m2c mrx(float t) {
  float c = cosf(0.5f * t), s = sinf(0.5f * t);
  return { {c, 0.f}, {0.f, -s}, {0.f, -s}, {c, 0.f} };
}
__device__ __forceinline__ m2c mrz(float t) {
  float c = cosf(0.5f * t), s = sinf(0.5f * t);
  return { {c, -s}, {0.f, 0.f}, {0.f, 0.f}, {c, s} };
}

// fusable(d,i): CU[i](d) absorbs U1[i](d+1). r(d)=1 (d even): i>=1; r=3: i>=3.
__device__ __forceinline__ bool fusable(int d, int i) {
  return (d & 1) ? (i >= 3) : (i >= 1);
}

// 69-op program, 64 floats/op.
//  bt>=7 (k-register target, wires 0..2): matrix form, M0@o[0], M1@o[16].
//  else: coef form, 4 variants v = hi + 2*c at o[v*8].
//  M0/M1: unfused no-ctrl: both adj; unfused ctrl: {I, adj(CU)};
//  fused: {adj(U1), adj(CU)*adj(U1)}.
// Thread 127 zeroes out[0] (nll atomicAdds into it each call).
__global__ void make_prog(const float* __restrict__ w, const float* __restrict__ w1,
                          const float* __restrict__ w2, float* __restrict__ prog,
                          float* __restrict__ outp) {
  const int t = threadIdx.x;
  if (t == 127) outp[0] = 0.f;
  int kind = -1, od = 0, oi = 0, p = 0;
  for (int dd = 0; dd < 5; ++dd) {
    const int d = 4 - dd;
    if (d == 4) { if (p == t) kind = 0; ++p; }
    for (int ii = 0; ii < 10; ++ii) {
      const int i = 9 - ii;
      if (p == t) { kind = (d <= 3 && fusable(d, i)) ? 2 : 1; od = d; oi = i; }
      ++p;
    }
    for (int ii = 0; ii < 10; ++ii) {
      const int i = 9 - ii;
      if (d >= 1 && fusable(d - 1, i)) continue;
      if (p == t) { kind = 3; od = d; oi = i; }
      ++p;
    }
  }
  if (kind < 0) return;

  auto u1mat = [&](int d, int i) -> m2c {
    const float* pw = w + (d * 10 + i) * 5;
    m2c U = mmul(mrx(pw[2]), mmul(mrz(pw[1]), mrx(pw[0])));
    if (i == 0 && d > 0) {
      m2c U0 = mmul(mrz(w2[d - 1]), mrx(w1[d - 1]));
      U = mmul(U, U0);
    }
    return U;
  };
  auto cumat = [&](int d, int i) -> m2c {
    const float* pw = w + (d * 10 + i) * 5;
    return mmul(mrx(pw[4]), mrz(pw[3]));
  };

  m2c M0{}, M1{};
  int bt = 9;
  if (kind == 0) {
    M0 = madj(mmul(mrz(w2[4]), mrx(w1[4]))); M1 = M0; bt = 9;
  } else if (kind == 1) {
    M1 = madj(cumat(od, oi));
    M0 = m2c{ {1.f, 0.f}, {0.f, 0.f}, {0.f, 0.f}, {1.f, 0.f} };
    bt = 9 - oi;
  } else if (kind == 2) {
    m2c V1 = madj(u1mat(od + 1, oi));
    m2c VC = madj(cumat(od, oi));
    M0 = V1; M1 = mmul(VC, V1);
    bt = 9 - oi;
  } else {
    M0 = madj(u1mat(od, oi)); M1 = M0; bt = 9 - oi;
  }

  float* o = prog + t * 64;
  if (bt >= 7) {
    const m2c* Ms[2] = {&M0, &M1};
    #pragma unroll
    for (int c = 0; c < 2; ++c) {
      const c2 e[4] = {Ms[c]->a00, Ms[c]->a01, Ms[c]->a10, Ms[c]->a11};
      #pragma unroll
      for (int q = 0; q < 4; ++q) {
        o[c*16 + q*4 + 0] = e[q].r; o[c*16 + q*4 + 1] = e[q].r;
        o[c*16 + q*4 + 2] = -e[q].i; o[c*16 + q*4 + 3] = e[q].i;
      }
    }
  } else {
    #pragma unroll
    for (int v = 0; v < 4; ++v) {
      const bool hi = (v & 1) != 0;
      const m2c& M = (v >> 1) ? M1 : M0;
      const c2 cA = hi ? M.a11 : M.a00;
      const c2 cB = hi ? M.a10 : M.a01;
      o[v*8+0] = cA.r; o[v*8+1] = cA.r; o[v*8+2] = -cA.i; o[v*8+3] = cA.i;
      o[v*8+4] = cB.r; o[v*8+5] = cB.r; o[v*8+6] = -cB.i; o[v*8+7] = cB.i;
    }
  }
}

struct CoefP { f32x2 Ar, Ai, Br, Bi; };
__device__ __forceinline__ CoefP ldcoef(const float* __restrict__ g, int v) {
  const float4* p = reinterpret_cast<const float4*>(g + v * 8);
  const float4 a = p[0], b = p[1];
  return { f32x2{a.x, a.y}, f32x2{a.z, a.w}, f32x2{b.x, b.y}, f32x2{b.z, b.w} };
}
struct MatP { f32x2 u00r, u00i, u01r, u01i, u10r, u10i, u11r, u11i; };
__device__ __forceinline__ MatP ldmat16(const float* __restrict__ g, int c) {
  const float4* p = reinterpret_cast<const float4*>(g + c * 16);
  const float4 a = p[0], b = p[1], cc = p[2], d = p[3];
  MatP m;
  m.u00r = f32x2{a.x, a.y};  m.u00i = f32x2{a.z, a.w};
  m.u01r = f32x2{b.x, b.y};  m.u01i = f32x2{b.z, b.w};
  m.u10r = f32x2{cc.x, cc.y}; m.u10i = f32x2{cc.z, cc.w};
  m.u11r = f32x2{d.x, d.y};  m.u11i = f32x2{d.z, d.w};
  return m;
}
__device__ __forceinline__ f32x2 capply(const CoefP& c, f32x2 own, f32x2 par) {
  return cmad(cmulp(c.Ar, c.Ai, own), c.Br, c.Bi, par);
}
__device__ __forceinline__ void mat_pair(const MatP& m, f32x2& a, f32x2& b) {
  const f32x2 na = cmad(cmulp(m.u00r, m.u00i, a), m.u01r, m.u01i, b);
  const f32x2 nb = cmad(cmulp(m.u10r, m.u10i, a), m.u11r, m.u11i, b);
  a = na; b = nb;
}

// One program op. j = (k<<7)|(wv<<6)|lane, k in [0,8), wv in {0,1}.
//   bt>=7: k-register pair (tm = 1<<(bt-7)), matrix form.
//   bt==6: cross-wave exchange (partner wv^1), coef form, 1 barrier.
//   bt<6: lane shuffle (lm = 1<<bt), coef form.
// ctrl bc: >=7 per-k (cb=bc-7); ==6 wave-uniform (c=wv); [0,6) per-lane; <0 none.
__device__ __forceinline__ void apply_op(f32x2 (&s)[8], f32x2* lxb, const int wv,
                                         const int lane, const float* __restrict__ g,
                                         const int bt, const int bc) {
  if (bt >= 7) {
    const int tm = 1 << (bt - 7);
    if (bc >= 7) {
      const int cb = bc - 7;
      const MatP m0 = ldmat16(g, 0), m1 = ldmat16(g, 1);
      #pragma unroll
      for (int k0 = 0; k0 < 8; ++k0) {
        if (k0 & tm) continue;
        const int k1 = k0 | tm;
        const MatP& m = ((k0 >> cb) & 1) ? m1 : m0;
        mat_pair(m, s[k0], s[k1]);
      }
    } else {
      int c = 0;
      if (bc == 6)      c = wv;
      else if (bc >= 0) c = (lane >> bc) & 1;
      const MatP m = ldmat16(g, c);
      #pragma unroll
      for (int k0 = 0; k0 < 8; ++k0) {
        if (k0 & tm) continue;
        const int k1 = k0 | tm;
        mat_pair(m, s[k0], s[k1]);
      }
    }
  } else if (bt == 6) {
    const int hi = wv;
    #pragma unroll
    for (int k = 0; k < 8; ++k) lxb[(wv * 8 + k) * 64 + lane] = s[k];
    __syncthreads();
    const int pw = wv ^ 1;
    f32x2 pp[8];
    #pragma unroll
    for (int k = 0; k < 8; ++k) pp[k] = lxb[(pw * 8 + k) * 64 + lane];
    if (bc >= 7) {
      const int cb = bc - 7;
      const CoefP c0 = ldcoef(g, hi), c1 = ldcoef(g, hi + 2);
      #pragma unroll
      for (int k = 0; k < 8; ++k) {
        const CoefP& cf = ((k >> cb) & 1) ? c1 : c0;
        s[k] = capply(cf, s[k], pp[k]);
      }
    } else {
      int c = 0;
      if (bc >= 0) c = (lane >> bc) & 1;   // bc==6 impossible (== bt)
      const CoefP cf = ldcoef(g, hi + 2 * c);
      #pragma unroll
      for (int k = 0; k < 8; ++k) s[k] = capply(cf, s[k], pp[k]);
    }
  } else {
    const int lm = 1 << bt;
    const int hi = (lane >> bt) & 1;
    if (bc >= 7) {
      const int cb = bc - 7;
      const CoefP c0 = ldcoef(g, hi), c1 = ldcoef(g, hi + 2);
      #pragma unroll
      for (int k = 0; k < 8; ++k) {
        const CoefP& cf = ((k >> cb) & 1) ? c1 : c0;
        const f32x2 p = shfl_fast(s[k], lm);
        s[k] = capply(cf, s[k], p);
      }
    } else {
      int c = 0;
      if (bc == 6)      c = wv;
      else if (bc >= 0) c = (lane >> bc) & 1;
      const CoefP cf = ldcoef(g, hi + 2 * c);
      #pragma unroll
      for (int k = 0; k < 8; ++k) {
        const f32x2 p = shfl_fast(s[k], lm);
        s[k] = capply(cf, s[k], p);
      }
    }
  }
}

// Fused prep, 128-thread blocks. Blocks <1024: build row n=blockIdx of U.
// Blocks >=1024: xconv one batch row (832 cols, packed cvt).
__global__ __launch_bounds__(128) void qprep(const float* __restrict__ prog,
                                             const float* __restrict__ x,
                                             _Float16* __restrict__ Wt,
                                             _Float16* __restrict__ Xh) {
  const int tid = threadIdx.x;
  if (blockIdx.x >= 1024) {
    const int b = blockIdx.x - 1024;   // batch row
    const int j = tid * 8;
    if (j >= 832) return;
    union { fp16x2 h2[4]; f16x8 h8; } u;
    if (j < 784) {
      const float4* p = reinterpret_cast<const float4*>(x + (size_t)b * 784 + j);
      const float4 v0 = p[0], v1 = p[1];
      u.h2[0] = __builtin_amdgcn_cvt_pkrtz(v0.x, v0.y);
      u.h2[1] = __builtin_amdgcn_cvt_pkrtz(v0.z, v0.w);
      u.h2[2] = __builtin_amdgcn_cvt_pkrtz(v1.x, v1.y);
      u.h2[3] = __builtin_amdgcn_cvt_pkrtz(v1.z, v1.w);
    } else {
      #pragma unroll
      for (int q = 0; q < 4; ++q) u.h2[q] = __builtin_amdgcn_cvt_pkrtz(0.f, 0.f);
    }
    *reinterpret_cast<f16x8*>(Xh + (size_t)b * 1024 + j) = u.h8;
    return;
  }

  // ---- build_W: 1 state, 8 regs/lane, 2 waves ----
  __shared__ f32x2 lx[2][1024];   // double-buffered exchange (2 x 8 KB)

  const int lane = tid & 63;
  const int wv = tid >> 6;        // 0..1 = j-bit 6
  const int n = blockIdx.x;

  f32x2 s[8];
  #pragma unroll
  for (int k = 0; k < 8; ++k) {
    const int j = (k << 7) | (wv << 6) | lane;
    s[k].x = (j == n) ? 1.f : 0.f;
    s[k].y = 0.f;
  }

  int p = 0, ph = 0;
  #pragma unroll
  for (int dd = 0; dd < 5; ++dd) {
    const int d = 4 - dd;
    if (d == 4) {
      apply_op(s, &lx[ph & 1][0], wv, lane, prog + p * 64, 9, -1);
      ++p;   // bt=9: k-reg op
    }
    const int r = (d & 1) ? 3 : 1;
    #pragma unroll
    for (int ii = 0; ii < 10; ++ii) {
      const int i = 9 - ii;
      const int c = (i + r) % 10;
      const int bt = 9 - i, bc = 9 - c;
      apply_op(s, &lx[ph & 1][0], wv, lane, prog + p * 64, bt, bc);
      ++p; if (bt == 6) ++ph;
    }
    #pragma unroll
    for (int ii = 0; ii < 10; ++ii) {
      const int i = 9 - ii;
      if (d >= 1 && fusable(d - 1, i)) continue;   // absorbed forward
      const int bt = 9 - i;
      apply_op(s, &lx[ph & 1][0], wv, lane, prog + p * 64, bt, -1);
      ++p; if (bt == 6) ++ph;
    }
  }

  // psi = U^dagger e_n => U[n][j] = (s.x, -s.y); j = (k<<7)|(wv<<6)|lane
  #pragma unroll
  for (int k = 0; k < 8; ++k) {
    const int j = (k << 7) | (wv << 6) | lane;
    Wt[(size_t)(2 * n) * 1024 + j] = (_Float16)s[k].x;
    Wt[(size_t)(2 * n + 1) * 1024 + j] = (_Float16)(-s[k].y);
  }
}

// ---------------- LDS-staged GEMM (unchanged from R11) ----------------
#define GZ_NSTEP 13

__device__ __forceinline__ void stage_tiles(const _Float16* __restrict__ gA,
                                            const _Float16* __restrict__ gB,
                                            _Float16* sA, _Float16* sB,
                                            int k0, int wv, int lane) {
  const int rIn = lane >> 3;
  const int colh = ((lane & 7) ^ rIn) * 8;
  #pragma unroll
  for (int c = 0; c < 2; ++c) {
    const int chunk = wv * 2 + c;
    const size_t grow = (size_t)(chunk * 8 + rIn) * 1024 + k0 + colh;
    auto* la = (__attribute__((address_space(3))) void*)(sA + chunk * 512 + lane * 8);
    __builtin_amdgcn_global_load_lds(
        (const __attribute__((address_space(1))) void*)(gA + grow), la, 16, 0, 0);
    auto* lb = (__attribute__((address_space(3))) void*)(sB + chunk * 512 + lane * 8);
    __builtin_amdgcn_global_load_lds(
        (const __attribute__((address_space(1))) void*)(gB + grow), lb, 16, 0, 0);
  }
}

__device__ __forceinline__ int lds_off(int row, int slot) {
  return row * 64 + ((slot ^ (row & 7)) * 8);
}

__global__ __launch_bounds__(512) void gemm_z(const _Float16* __restrict__ Xh,
                                              const _Float16* __restrict__ Wt,
                                              float* __restrict__ part, int B) {
  __shared__ _Float16 smA[2][128 * 64];
  __shared__ _Float16 smB[2][128 * 64];

  const int tid = threadIdx.x;
  const int lane = tid & 63;
  const int wv = tid >> 6;
  const int wm = wv >> 1;
  const int wn = wv & 1;
  const int row0 = blockIdx.x * 128;
  const int n0 = blockIdx.y * 128;

  const _Float16* gA = Xh + (size_t)row0 * 1024;
  const _Float16* gB = Wt + (size_t)n0 * 1024;

  const int lr = lane & 15;
  const int lq = lane >> 4;

  f32x4v acc[2][4];
  #pragma unroll
  for (int m = 0; m < 2; ++m)
    #pragma unroll
    for (int f = 0; f < 4; ++f) acc[m][f] = f32x4v{0.f, 0.f, 0.f, 0.f};

  stage_tiles(gA, gB, smA[0], smB[0], 0, wv, lane);
  __syncthreads();

  for (int t = 0; t < GZ_NSTEP; ++t) {
    const int cur = t & 1;
    if (t + 1 < GZ_NSTEP)
      stage_tiles(gA, gB, smA[cur ^ 1], smB[cur ^ 1], (t + 1) * 64, wv, lane);

    #pragma unroll
    for (int kk = 0; kk < 2; ++kk) {
      const int slot = kk * 4 + lq;
      f16x8 a[2], b[4];
      #pragma unroll
      for (int m = 0; m < 2; ++m) {
        const int row = wm * 32 + m * 16 + lr;
        a[m] = *reinterpret_cast<const f16x8*>(&smA[cur][lds_off(row, slot)]);
      }
      #pragma unroll
      for (int f = 0; f < 4; ++f) {
        const int row = wn * 64 + f * 16 + lr;
        b[f] = *reinterpret_cast<const f16x8*>(&smB[cur][lds_off(row, slot)]);
      }
      #pragma unroll
      for (int m = 0; m < 2; ++m)
        #pragma unroll
        for (int f = 0; f < 4; ++f)
          acc[m][f] = __builtin_amdgcn_mfma_f32_16x16x32_f16(a[m], b[f], acc[m][f], 0, 0, 0);
    }
    __syncthreads();
  }

  const int pp = blockIdx.y * 2 + wn;
  #pragma unroll
  for (int m = 0; m < 2; ++m) {
    f32x4v p = f32x4v{0.f, 0.f, 0.f, 0.f};
    #pragma unroll
    for (int f = 0; f < 4; ++f) p += acc[m][f] * acc[m][f];
    #pragma unroll
    for (int msk = 1; msk < 16; msk <<= 1) {
      p.x += __shfl_xor(p.x, msk, 64);
      p.y += __shfl_xor(p.y, msk, 64);
      p.z += __shfl_xor(p.z, msk, 64);
      p.w += __shfl_xor(p.w, msk, 64);
    }
    if (lr == 0) {
      const int rbase = row0 + wm * 32 + m * 16 + lq * 4;
      float* dst = part + (size_t)pp * B + rbase;
      dst[0] = p.x; dst[1] = p.y; dst[2] = p.z; dst[3] = p.w;
    }
  }
}

// ---- NLL: per-block partial, atomicAdd of scaled sum into out[0] ----
__global__ __launch_bounds__(256) void nll_part(const float* __restrict__ part,
                                                const int* __restrict__ y,
                                                float* __restrict__ out, int B,
                                                float scale) {
  const int row = blockIdx.x * 256 + threadIdx.x;
  float q0 = 0.f, q1 = 0.f, nn = 0.f;
  #pragma unroll
  for (int pp = 0; pp < 32; ++pp) {
    const float P = part[(size_t)pp * B + row];
    q0 += (pp & 16) ? -P : P;
    q1 += (pp & 8) ? -P : P;
    nn += P;
  }
  const float z0 = q0 / nn, z1 = q1 / nn;
  const float mx = fmaxf(z0, z1);
  const float lse = mx + logf(expf(z0 - mx) + expf(z1 - mx));
  const float ly = (y[row] == 0) ? z0 : z1;
  float s = lse - ly;
  #pragma unroll
  for (int msk = 1; msk < 64; msk <<= 1) s += __shfl_xor(s, msk, 64);
  __shared__ float red[4];
  if ((threadIdx.x & 63) == 0) red[threadIdx.x >> 6] = s;
  __syncthreads();
  if (threadIdx.x == 0)
    atomicAdd(out, (red[0] + red[1] + red[2] + red[3]) * scale);
}

} // namespace

extern "C" void kernel_launch(void* const* d_in, const int* in_sizes, int n_in,
                              void* d_out, int out_size, void* d_ws, size_t ws_size,
                              hipStream_t stream) {
  const float* x  = (const float*)d_in[0];
  const int*   y  = (const int*)d_in[1];
  const float* w  = (const float*)d_in[2];
  const float* w1 = (const float*)d_in[3];
  const float* w2 = (const float*)d_in[4];
  float* out = (float*)d_out;

  const int B = in_sizes[0] / 784;      // 8192

  char* ws = (char*)d_ws;
  _Float16* Wt   = (_Float16*)ws;                                // 4 MB
  _Float16* Xh   = (_Float16*)(ws + (size_t)2048 * 1024 * 2);    // 16 MB
  float*    part = (float*)(ws + (size_t)2048 * 1024 * 2 + (size_t)B * 1024 * 2);
  float*    prog = part + (size_t)32 * B;   // 69*64 floats

  make_prog<<<1, 128, 0, stream>>>(w, w1, w2, prog, out);
  qprep<<<1024 + B, 128, 0, stream>>>(prog, x, Wt, Xh);
  gemm_z<<<dim3(B / 128, 16), 512, 0, stream>>>(Xh, Wt, part, B);
  nll_part<<<B / 256, 256, 0, stream>>>(part, y, out, B, 1.0f / (float)B);
}